// Round 8
// baseline (760.758 us; speedup 1.0000x reference)
//
#include <hip/hip_runtime.h>
#include <hip/hip_bf16.h>

#define DD 128

typedef short bf16x8 __attribute__((ext_vector_type(8)));
typedef unsigned short u16x8 __attribute__((ext_vector_type(8)));
typedef float f32x4 __attribute__((ext_vector_type(4)));

__device__ __forceinline__ float sigmoidf_(float v){ return 1.f/(1.f+__expf(-v)); }
__device__ __forceinline__ float tanhf_(float v){
  float e2 = __expf(2.f*v);
  return 1.f - 2.f/(e2 + 1.f);
}
__device__ __forceinline__ float b2f(unsigned short u){
  unsigned int x = ((unsigned int)u) << 16;
  union { unsigned int i; float f; } c; c.i = x; return c.f;
}
__device__ __forceinline__ void bsplit(float v, unsigned short& hi, unsigned short& lo){
  __hip_bfloat16 h = __float2bfloat16(v);
  float hf = __bfloat162float(h);
  __hip_bfloat16 l = __float2bfloat16(v - hf);
  hi = *(unsigned short*)&h;
  lo = *(unsigned short*)&l;
}

// ---------- weight prep: GRU weights -> bf16 hi/lo B-frag order + decoder transpose ----------
// Tile nt in [0,24): fg = nt/3, gate = nt%3. Column j = gate*128 + fg*16 + (l&15).
// frag index fi = (((nt*4+ks)*64)+l)*8 + t ; k = ks*32 + ((l>>4)&3)*8 + t
__global__ void k_prep_frag(const float* __restrict__ W_ih, const float* __restrict__ W_hh,
                            const float* __restrict__ W_dec,
                            unsigned short* __restrict__ Wih_hi, unsigned short* __restrict__ Wih_lo,
                            unsigned short* __restrict__ Whh_hi, unsigned short* __restrict__ Whh_lo,
                            float* __restrict__ Wt_dec){
  int idx = blockIdx.x*256 + threadIdx.x;
  const int TOT = 384*128;
  if (idx < 2*TOT){
    const float* W = (idx < TOT) ? W_ih : W_hh;
    unsigned short* Dh = (idx < TOT) ? Wih_hi : Whh_hi;
    unsigned short* Dl = (idx < TOT) ? Wih_lo : Whh_lo;
    int fi = (idx < TOT) ? idx : idx - TOT;
    int t = fi & 7;
    int l = (fi >> 3) & 63;
    int ks = (fi >> 9) & 3;
    int nt = fi >> 11;
    int fg = nt / 3, gate = nt % 3;
    int j = gate*128 + fg*16 + (l & 15);
    int k = ks*32 + ((l >> 4) & 3)*8 + t;
    unsigned short hi, lo;
    bsplit(W[j*128 + k], hi, lo);
    Dh[fi] = hi; Dl[fi] = lo;
  } else if (idx < 2*TOT + 64*128){
    int t2 = idx - 2*TOT;
    int j = t2 / 128, k = t2 % 128;
    int o = ((k>>2)*64 + j)*4 + (k&3);
    Wt_dec[o] = W_dec[t2];
  }
}

// ---------- encoder ----------
__global__ void __launch_bounds__(128) k_enc(const float* __restrict__ x,
                        const float* __restrict__ W_enc,
                        float* __restrict__ h0, float* __restrict__ stats, int N){
  const int f = threadIdx.x;
  const float w0 = W_enc[f*3], w1 = W_enc[f*3+1], w2 = W_enc[f*3+2];
  const int chunk = (N + gridDim.x - 1) / gridDim.x;
  const int n0 = blockIdx.x * chunk;
  const int n1 = (n0 + chunk < N) ? (n0 + chunk) : N;
  float s = 0.f, q = 0.f;
  for (int n = n0; n < n1; n++){
    float x0 = x[n*3], x1 = x[n*3+1], x2 = x[n*3+2];
    float h = x0*w0 + x1*w1 + x2*w2;
    h0[(size_t)n*DD + f] = h;
    s += h; q += h*h;
  }
  atomicAdd(&stats[f], s);
  atomicAdd(&stats[DD+f], q);
}

__global__ void k_enc_apply(const float* __restrict__ h0, const float* __restrict__ gamma,
                            const float* __restrict__ beta, const float* __restrict__ stats,
                            unsigned short* __restrict__ hs_hi, unsigned short* __restrict__ hs_lo,
                            unsigned short* __restrict__ ph_hi, unsigned short* __restrict__ ph_lo, int N){
  int idx = blockIdx.x*256 + threadIdx.x;
  if (idx >= N*DD) return;
  int f = idx & (DD-1);
  float invN = 1.f / (float)N;
  float mu = stats[f] * invN;
  float var = stats[DD+f] * invN - mu*mu;
  float v = (h0[idx] - mu) * rsqrtf(var + 1e-5f) * gamma[f] + beta[f];
  v = fmaxf(v, 0.f);
  unsigned short hi, lo; bsplit(v, hi, lo);
  ph_hi[idx] = hi; ph_lo[idx] = lo;
  hs_hi[idx] = hi; hs_lo[idx] = lo;
}

// ---------- CSR build (1-level) ----------
__global__ void k_hist(const int* __restrict__ dst, int* __restrict__ counts, int E){
  int e = blockIdx.x*256 + threadIdx.x;
  if (e < E) atomicAdd(&counts[dst[e]], 1);
}

__global__ void __launch_bounds__(256) k_scan_part(const int* __restrict__ counts,
                                                   int* __restrict__ partials, int N){
  int i = blockIdx.x*256 + threadIdx.x;
  int v = (i < N) ? counts[i] : 0;
  #pragma unroll
  for (int off = 32; off > 0; off >>= 1) v += __shfl_down(v, off, 64);
  __shared__ int red[4];
  if ((threadIdx.x & 63) == 0) red[threadIdx.x >> 6] = v;
  __syncthreads();
  if (threadIdx.x == 0) partials[blockIdx.x] = red[0]+red[1]+red[2]+red[3];
}

__global__ void __launch_bounds__(256) k_scan_mid(int* __restrict__ partials, int P,
                                                  int* __restrict__ offsets, int N){
  __shared__ int lds[4];
  __shared__ int carry_s;
  const int lane = threadIdx.x & 63, wid = threadIdx.x >> 6;
  if (threadIdx.x == 0) carry_s = 0;
  __syncthreads();
  for (int base = 0; base < P; base += 256){
    int i = base + threadIdx.x;
    int v = (i < P) ? partials[i] : 0;
    int orig = v;
    #pragma unroll
    for (int off = 1; off < 64; off <<= 1){
      int u = __shfl_up(v, off, 64);
      if (lane >= off) v += u;
    }
    if (lane == 63) lds[wid] = v;
    __syncthreads();
    if (threadIdx.x == 0){
      int s = carry_s;
      for (int k = 0; k < 4; k++){ int t = lds[k]; lds[k] = s; s += t; }
      carry_s = s;
    }
    __syncthreads();
    int excl = v - orig + lds[wid];
    if (i < P) partials[i] = excl;
    __syncthreads();
  }
  if (threadIdx.x == 0) offsets[N] = carry_s;
}

__global__ void __launch_bounds__(256) k_scan_expand(const int* __restrict__ counts,
        const int* __restrict__ partials, int* __restrict__ offsets,
        int* __restrict__ cursors, int N){
  int i = blockIdx.x*256 + threadIdx.x;
  int v = (i < N) ? counts[i] : 0;
  int orig = v;
  const int lane = threadIdx.x & 63, wid = threadIdx.x >> 6;
  #pragma unroll
  for (int off = 1; off < 64; off <<= 1){
    int u = __shfl_up(v, off, 64);
    if (lane >= off) v += u;
  }
  __shared__ int lds[4];
  if (lane == 63) lds[wid] = v;
  __syncthreads();
  int wbase = 0;
  for (int k = 0; k < wid; k++) wbase += lds[k];
  int excl = partials[blockIdx.x] + wbase + v - orig;
  if (i < N){ offsets[i] = excl; cursors[i] = excl; }
}

__global__ void k_fill(const int* __restrict__ src, const int* __restrict__ dst,
                       const float* __restrict__ norm, int* __restrict__ cursors,
                       int* __restrict__ csr_src, float* __restrict__ csr_norm, int E){
  int e = blockIdx.x*256 + threadIdx.x;
  if (e >= E) return;
  int p = atomicAdd(&cursors[dst[e]], 1);
  csr_src[p] = src[e];
  csr_norm[p] = norm[e];
}

// ---------- fused layer: bf16 gather -> LDS -> MFMA -> gates ----------
// h lives ONLY as bf16 hi/lo (double-buffered); h_sum also bf16 hi/lo.
// 256 threads. Phase1: 16 node-slots x 16 lanes x 2 passes; h_sum RMW fused.
// Phase2+3: wave w handles fg = 2w, 2w+1; A(agg) from LDS, A(ph) hi/lo global.
// LDS swizzle: 16B chunk c of row m at c^(m&7).
__global__ void __launch_bounds__(256, 4) k_layer(
        const unsigned short* __restrict__ phc_hi, const unsigned short* __restrict__ phc_lo,
        unsigned short* __restrict__ phn_hi, unsigned short* __restrict__ phn_lo,
        unsigned short* __restrict__ hs_hi, unsigned short* __restrict__ hs_lo,
        const int* __restrict__ offsets, const int* __restrict__ csr_src,
        const float* __restrict__ csr_norm,
        const unsigned short* __restrict__ Wih_hi, const unsigned short* __restrict__ Wih_lo,
        const unsigned short* __restrict__ Whh_hi, const unsigned short* __restrict__ Whh_lo,
        const float* __restrict__ b_ih, const float* __restrict__ b_hh, int N){
  __shared__ unsigned short s_ah[32*DD];
  __shared__ unsigned short s_al[32*DD];
  const int tid = threadIdx.x;
  const int n0 = blockIdx.x * 32;

  // ---- phase 1: gather (bf16 rows) ----
  {
    const int slot = tid >> 4;   // node slot 0..15
    const int q    = tid & 15;   // feature octet
    #pragma unroll
    for (int pass = 0; pass < 2; pass++){
      const int m = slot + pass*16;
      const int n = n0 + m;
      float acc[8];
      #pragma unroll
      for (int t = 0; t < 8; t++) acc[t] = 0.f;
      if (n < N){
        const int s0 = offsets[n], s1 = offsets[n+1];
        int i = s0;
        for (; i + 8 <= s1; i += 8){
          int sE[8]; float wE[8]; bf16x8 R[8];
          #pragma unroll
          for (int u = 0; u < 8; u++){ sE[u] = csr_src[i+u]; wE[u] = csr_norm[i+u]; }
          #pragma unroll
          for (int u = 0; u < 8; u++) R[u] = *(const bf16x8*)(phc_hi + (size_t)sE[u]*DD + q*8);
          #pragma unroll
          for (int u = 0; u < 8; u++)
            #pragma unroll
            for (int t = 0; t < 8; t++)
              acc[t] = fmaf(wE[u], b2f((unsigned short)R[u][t]), acc[t]);
        }
        if (i + 4 <= s1){
          int sE[4]; float wE[4]; bf16x8 R[4];
          #pragma unroll
          for (int u = 0; u < 4; u++){ sE[u] = csr_src[i+u]; wE[u] = csr_norm[i+u]; }
          #pragma unroll
          for (int u = 0; u < 4; u++) R[u] = *(const bf16x8*)(phc_hi + (size_t)sE[u]*DD + q*8);
          #pragma unroll
          for (int u = 0; u < 4; u++)
            #pragma unroll
            for (int t = 0; t < 8; t++)
              acc[t] = fmaf(wE[u], b2f((unsigned short)R[u][t]), acc[t]);
          i += 4;
        }
        for (; i < s1; i++){
          int s = csr_src[i];
          float w = csr_norm[i];
          bf16x8 R = *(const bf16x8*)(phc_hi + (size_t)s*DD + q*8);
          #pragma unroll
          for (int t = 0; t < 8; t++)
            acc[t] = fmaf(w, b2f((unsigned short)R[t]), acc[t]);
        }
        // h_sum RMW in bf16 hi/lo (coalesced 16B vectors)
        size_t o = (size_t)n*DD + q*8;
        u16x8 shi = *(const u16x8*)(hs_hi + o);
        u16x8 slo = *(const u16x8*)(hs_lo + o);
        #pragma unroll
        for (int t = 0; t < 8; t++){
          float s = b2f(shi[t]) + b2f(slo[t]) + acc[t];
          unsigned short hi, lo; bsplit(s, hi, lo);
          shi[t] = hi; slo[t] = lo;
        }
        *(u16x8*)(hs_hi + o) = shi;
        *(u16x8*)(hs_lo + o) = slo;
      }
      u16x8 vhi, vlo;
      #pragma unroll
      for (int t = 0; t < 8; t++){
        unsigned short hi, lo; bsplit(acc[t], hi, lo);
        vhi[t] = hi; vlo[t] = lo;
      }
      const int cc = q ^ (m & 7);
      const int off = m*DD + cc*8;
      *(u16x8*)(s_ah + off) = vhi;
      *(u16x8*)(s_al + off) = vlo;
    }
  }
  __syncthreads();   // the only barrier: LDS A-frags ready

  // ---- phase 2+3 per feature group ----
  const int w = tid >> 6, l = tid & 63, ar = l & 15, aq = l >> 4;
  int r0 = n0 + ar;      if (r0 >= N) r0 = N-1;
  int r1 = n0 + 16 + ar; if (r1 >= N) r1 = N-1;
  const size_t p0 = (size_t)r0*DD + aq*8;
  const size_t p1 = (size_t)r1*DD + aq*8;
  const int sw = ar & 7;

  for (int g = 0; g < 2; g++){
    const int fg = w*2 + g;
    f32x4 acc_i[2][3], acc_h[2][3];
    #pragma unroll
    for (int ta = 0; ta < 2; ta++)
      #pragma unroll
      for (int t = 0; t < 3; t++){
        acc_i[ta][t] = (f32x4){0.f,0.f,0.f,0.f};
        acc_h[ta][t] = (f32x4){0.f,0.f,0.f,0.f};
      }

    #pragma unroll
    for (int ks = 0; ks < 4; ks++){
      const int c = (ks*4 + aq) ^ sw;
      bf16x8 ih0 = *(const bf16x8*)(s_ah + ar*DD       + c*8);
      bf16x8 ih1 = *(const bf16x8*)(s_ah + (16+ar)*DD  + c*8);
      bf16x8 il0 = *(const bf16x8*)(s_al + ar*DD       + c*8);
      bf16x8 il1 = *(const bf16x8*)(s_al + (16+ar)*DD  + c*8);
      bf16x8 hh0 = *(const bf16x8*)(phc_hi + p0 + ks*32);
      bf16x8 hh1 = *(const bf16x8*)(phc_hi + p1 + ks*32);
      bf16x8 hl0 = *(const bf16x8*)(phc_lo + p0 + ks*32);
      bf16x8 hl1 = *(const bf16x8*)(phc_lo + p1 + ks*32);
      #pragma unroll
      for (int t = 0; t < 3; t++){
        size_t bo = ((size_t)((fg*3 + t)*4 + ks)*64 + l)*8;
        bf16x8 bih = *(const bf16x8*)(Wih_hi + bo);
        bf16x8 bil = *(const bf16x8*)(Wih_lo + bo);
        bf16x8 bhh = *(const bf16x8*)(Whh_hi + bo);
        bf16x8 bhl = *(const bf16x8*)(Whh_lo + bo);
        acc_i[0][t] = __builtin_amdgcn_mfma_f32_16x16x32_bf16(ih0, bih, acc_i[0][t], 0, 0, 0);
        acc_i[0][t] = __builtin_amdgcn_mfma_f32_16x16x32_bf16(ih0, bil, acc_i[0][t], 0, 0, 0);
        acc_i[0][t] = __builtin_amdgcn_mfma_f32_16x16x32_bf16(il0, bih, acc_i[0][t], 0, 0, 0);
        acc_i[1][t] = __builtin_amdgcn_mfma_f32_16x16x32_bf16(ih1, bih, acc_i[1][t], 0, 0, 0);
        acc_i[1][t] = __builtin_amdgcn_mfma_f32_16x16x32_bf16(ih1, bil, acc_i[1][t], 0, 0, 0);
        acc_i[1][t] = __builtin_amdgcn_mfma_f32_16x16x32_bf16(il1, bih, acc_i[1][t], 0, 0, 0);
        acc_h[0][t] = __builtin_amdgcn_mfma_f32_16x16x32_bf16(hh0, bhh, acc_h[0][t], 0, 0, 0);
        acc_h[0][t] = __builtin_amdgcn_mfma_f32_16x16x32_bf16(hh0, bhl, acc_h[0][t], 0, 0, 0);
        acc_h[0][t] = __builtin_amdgcn_mfma_f32_16x16x32_bf16(hl0, bhh, acc_h[0][t], 0, 0, 0);
        acc_h[1][t] = __builtin_amdgcn_mfma_f32_16x16x32_bf16(hh1, bhh, acc_h[1][t], 0, 0, 0);
        acc_h[1][t] = __builtin_amdgcn_mfma_f32_16x16x32_bf16(hh1, bhl, acc_h[1][t], 0, 0, 0);
        acc_h[1][t] = __builtin_amdgcn_mfma_f32_16x16x32_bf16(hl1, bhh, acc_h[1][t], 0, 0, 0);
      }
    }

    const int f = fg*16 + ar;
    const float bir = b_ih[f], biz = b_ih[128+f], bin_ = b_ih[256+f];
    const float bhr = b_hh[f], bhz = b_hh[128+f], bhn = b_hh[256+f];
    #pragma unroll
    for (int ta = 0; ta < 2; ta++){
      #pragma unroll
      for (int r = 0; r < 4; r++){
        int n = n0 + ta*16 + aq*4 + r;
        if (n < N){
          float sir = acc_i[ta][0][r] + bir, shr = acc_h[ta][0][r] + bhr;
          float siz = acc_i[ta][1][r] + biz, shz = acc_h[ta][1][r] + bhz;
          float sin_ = acc_i[ta][2][r] + bin_, shn = acc_h[ta][2][r] + bhn;
          float rr = sigmoidf_(sir + shr);
          float zz = sigmoidf_(siz + shz);
          float nn = tanhf_(sin_ + rr*shn);
          size_t o = (size_t)n*DD + f;
          float hp = b2f(phc_hi[o]) + b2f(phc_lo[o]);
          float h = (1.f - zz)*nn + zz*hp;
          unsigned short hi, lo; bsplit(h, hi, lo);
          phn_hi[o] = hi; phn_lo[o] = lo;
        }
      }
    }
  }
}

// ---------- decoder stage 1: 8 split stats copies ----------
__global__ void __launch_bounds__(256) k_dec1(const unsigned short* __restrict__ hs_hi,
        const unsigned short* __restrict__ hs_lo,
        const float* __restrict__ Wt_dec, float* __restrict__ y1,
        float* __restrict__ stats_d, int N){
  const int j = threadIdx.x & 63;
  const int slot = threadIdx.x >> 6;
  float s = 0.f, q = 0.f;
  for (int n = blockIdx.x*4 + slot; n < N; n += gridDim.x*4){
    float acc = 0.f;
    for (int k8 = 0; k8 < 16; k8++){
      u16x8 zh = *(const u16x8*)(hs_hi + (size_t)n*DD + k8*8);
      u16x8 zl = *(const u16x8*)(hs_lo + (size_t)n*DD + k8*8);
      float4 w0 = *(const float4*)(Wt_dec + ((size_t)(2*k8)*64 + j)*4);
      float4 w1 = *(const float4*)(Wt_dec + ((size_t)(2*k8+1)*64 + j)*4);
      acc += (b2f(zh[0])+b2f(zl[0]))*w0.x + (b2f(zh[1])+b2f(zl[1]))*w0.y
           + (b2f(zh[2])+b2f(zl[2]))*w0.z + (b2f(zh[3])+b2f(zl[3]))*w0.w
           + (b2f(zh[4])+b2f(zl[4]))*w1.x + (b2f(zh[5])+b2f(zl[5]))*w1.y
           + (b2f(zh[6])+b2f(zl[6]))*w1.z + (b2f(zh[7])+b2f(zl[7]))*w1.w;
    }
    acc *= (1.f/6.f);
    y1[(size_t)n*64 + j] = acc;
    s += acc; q += acc*acc;
  }
  __shared__ float red[2][4][64];
  red[0][slot][j] = s; red[1][slot][j] = q;
  __syncthreads();
  if (slot == 0){
    s = red[0][0][j] + red[0][1][j] + red[0][2][j] + red[0][3][j];
    q = red[1][0][j] + red[1][1][j] + red[1][2][j] + red[1][3][j];
    float* st = stats_d + (size_t)(blockIdx.x & 7)*128;
    atomicAdd(&st[j], s);
    atomicAdd(&st[64+j], q);
  }
}

// ---------- decoder stage 2: sum stats copies, bn + relu + dot ----------
__global__ void __launch_bounds__(256) k_dec2(const float* __restrict__ y1,
        const float* __restrict__ gamma, const float* __restrict__ beta,
        const float* __restrict__ W_dec2, const float* __restrict__ stats_d,
        float* __restrict__ out, int N){
  const int j = threadIdx.x & 63;
  const int g = threadIdx.x >> 6;
  const int n = blockIdx.x*4 + g;
  if (n >= N) return;
  float ssum = 0.f, qsum = 0.f;
  #pragma unroll
  for (int c = 0; c < 8; c++){
    ssum += stats_d[c*128 + j];
    qsum += stats_d[c*128 + 64 + j];
  }
  float invN = 1.f / (float)N;
  float mu = ssum * invN;
  float var = qsum * invN - mu*mu;
  float v = (y1[(size_t)n*64 + j] - mu) * rsqrtf(var + 1e-5f) * gamma[j] + beta[j];
  v = fmaxf(v, 0.f) * W_dec2[j];
  for (int off = 32; off > 0; off >>= 1) v += __shfl_down(v, off, 64);
  if (j == 0) out[n] = v;
}

extern "C" void kernel_launch(void* const* d_in, const int* in_sizes, int n_in,
                              void* d_out, int out_size, void* d_ws, size_t ws_size,
                              hipStream_t stream) {
  const int N = in_sizes[0] / 3;
  const int E = in_sizes[1] / 2;
  const int P = (N + 255) / 256;

  const float* x     = (const float*)d_in[0];
  const int*   ei    = (const int*)d_in[1];
  const int*   src   = ei;
  const int*   dst   = ei + E;
  const float* norm  = (const float*)d_in[2];
  const float* W_enc = (const float*)d_in[3];
  const float* g_e   = (const float*)d_in[4];
  const float* b_e   = (const float*)d_in[5];
  const float* W_ih  = (const float*)d_in[6];
  const float* W_hh  = (const float*)d_in[7];
  const float* b_ih  = (const float*)d_in[8];
  const float* b_hh  = (const float*)d_in[9];
  const float* W_dec = (const float*)d_in[10];
  const float* g_d   = (const float*)d_in[11];
  const float* b_d   = (const float*)d_in[12];
  const float* W_dec2= (const float*)d_in[13];
  float* out = (float*)d_out;

  float* ws = (float*)d_ws;
  const size_t NF = (size_t)N * DD;
  float* scr    = ws;                        // NF fp32: h0 (pre-loop) / y1 (post-loop)
  float* stats  = scr + NF;                  // 256 enc + 1024 dec
  float* Wt_dec = stats + 1280;              // 64*128
  unsigned short* Wih_hi = (unsigned short*)(Wt_dec + 64*128);
  unsigned short* Wih_lo = Wih_hi + 384*128;
  unsigned short* Whh_hi = Wih_lo + 384*128;
  unsigned short* Whh_lo = Whh_hi + 384*128;
  unsigned short* ph_hiA = Whh_lo + 384*128; // NF ushorts each
  unsigned short* ph_loA = ph_hiA + NF;
  unsigned short* ph_hiB = ph_loA + NF;
  unsigned short* ph_loB = ph_hiB + NF;
  unsigned short* hs_hi  = ph_loB + NF;      // NF ushorts (h_sum hi)
  unsigned short* hs_lo  = hs_hi + NF;       // NF ushorts (h_sum lo)
  int*   counts  = (int*)(hs_lo + NF);       // N
  int*   offsets = counts + N;               // N+1
  int*   cursors = offsets + N + 1;          // N
  int*   partials= cursors + N;              // P
  int*   csr_src = partials + P;             // E
  float* csr_norm = (float*)(csr_src + E);   // E
  float* h0 = scr;
  float* y1 = scr;

  hipMemsetAsync(stats, 0, 1280*sizeof(float), stream);
  hipMemsetAsync(counts, 0, (size_t)N*sizeof(int), stream);

  k_prep_frag<<<(2*384*128 + 64*128 + 255)/256, 256, 0, stream>>>(
      W_ih, W_hh, W_dec, Wih_hi, Wih_lo, Whh_hi, Whh_lo, Wt_dec);
  k_enc<<<256, 128, 0, stream>>>(x, W_enc, h0, stats, N);
  k_enc_apply<<<(N*DD + 255)/256, 256, 0, stream>>>(h0, g_e, b_e, stats, hs_hi, hs_lo, ph_hiA, ph_loA, N);

  k_hist<<<(E + 255)/256, 256, 0, stream>>>(dst, counts, E);
  k_scan_part<<<P, 256, 0, stream>>>(counts, partials, N);
  k_scan_mid<<<1, 256, 0, stream>>>(partials, P, offsets, N);
  k_scan_expand<<<P, 256, 0, stream>>>(counts, partials, offsets, cursors, N);
  k_fill<<<(E + 255)/256, 256, 0, stream>>>(src, dst, norm, cursors, csr_src, csr_norm, E);

  unsigned short* phh_c = ph_hiA; unsigned short* phl_c = ph_loA;
  unsigned short* phh_n = ph_hiB; unsigned short* phl_n = ph_loB;
  for (int l = 0; l < 5; l++){
    k_layer<<<(N + 31)/32, 256, 0, stream>>>(phh_c, phl_c, phh_n, phl_n, hs_hi, hs_lo,
                                             offsets, csr_src, csr_norm,
                                             Wih_hi, Wih_lo, Whh_hi, Whh_lo, b_ih, b_hh, N);
    { unsigned short* t = phh_c; phh_c = phh_n; phh_n = t; }
    { unsigned short* t = phl_c; phl_c = phl_n; phl_n = t; }
  }

  k_dec1<<<1024, 256, 0, stream>>>(hs_hi, hs_lo, Wt_dec, y1, stats + 256, N);
  k_dec2<<<(N + 3)/4, 256, 0, stream>>>(y1, g_d, b_d, W_dec2, stats + 256, out, N);
}

// Round 9
// 717.096 us; speedup vs baseline: 1.0609x; 1.0609x over previous
//
#include <hip/hip_runtime.h>
#include <hip/hip_bf16.h>

#define DD 128

typedef short bf16x8 __attribute__((ext_vector_type(8)));
typedef unsigned short u16x8 __attribute__((ext_vector_type(8)));
typedef float f32x4 __attribute__((ext_vector_type(4)));

__device__ __forceinline__ float sigmoidf_(float v){ return 1.f/(1.f+__expf(-v)); }
__device__ __forceinline__ float tanhf_(float v){
  float e2 = __expf(2.f*v);
  return 1.f - 2.f/(e2 + 1.f);
}
__device__ __forceinline__ float b2f(unsigned short u){
  unsigned int x = ((unsigned int)u) << 16;
  union { unsigned int i; float f; } c; c.i = x; return c.f;
}
__device__ __forceinline__ void bsplit(float v, unsigned short& hi, unsigned short& lo){
  __hip_bfloat16 h = __float2bfloat16(v);
  float hf = __bfloat162float(h);
  __hip_bfloat16 l = __float2bfloat16(v - hf);
  hi = *(unsigned short*)&h;
  lo = *(unsigned short*)&l;
}

// ---------- weight prep: GRU weights -> bf16 hi/lo B-frag order + decoder transpose ----------
// Tile nt in [0,24): fg = nt/3, gate = nt%3. Column j = gate*128 + fg*16 + (l&15).
// frag index fi = (((nt*4+ks)*64)+l)*8 + t ; k = ks*32 + ((l>>4)&3)*8 + t
__global__ void k_prep_frag(const float* __restrict__ W_ih, const float* __restrict__ W_hh,
                            const float* __restrict__ W_dec,
                            unsigned short* __restrict__ Wih_hi, unsigned short* __restrict__ Wih_lo,
                            unsigned short* __restrict__ Whh_hi, unsigned short* __restrict__ Whh_lo,
                            float* __restrict__ Wt_dec){
  int idx = blockIdx.x*256 + threadIdx.x;
  const int TOT = 384*128;
  if (idx < 2*TOT){
    const float* W = (idx < TOT) ? W_ih : W_hh;
    unsigned short* Dh = (idx < TOT) ? Wih_hi : Whh_hi;
    unsigned short* Dl = (idx < TOT) ? Wih_lo : Whh_lo;
    int fi = (idx < TOT) ? idx : idx - TOT;
    int t = fi & 7;
    int l = (fi >> 3) & 63;
    int ks = (fi >> 9) & 3;
    int nt = fi >> 11;
    int fg = nt / 3, gate = nt % 3;
    int j = gate*128 + fg*16 + (l & 15);
    int k = ks*32 + ((l >> 4) & 3)*8 + t;
    unsigned short hi, lo;
    bsplit(W[j*128 + k], hi, lo);
    Dh[fi] = hi; Dl[fi] = lo;
  } else if (idx < 2*TOT + 64*128){
    int t2 = idx - 2*TOT;
    int j = t2 / 128, k = t2 % 128;
    int o = ((k>>2)*64 + j)*4 + (k&3);
    Wt_dec[o] = W_dec[t2];
  }
}

// ---------- encoder ----------
__global__ void __launch_bounds__(128) k_enc(const float* __restrict__ x,
                        const float* __restrict__ W_enc,
                        float* __restrict__ h0, float* __restrict__ stats, int N){
  const int f = threadIdx.x;
  const float w0 = W_enc[f*3], w1 = W_enc[f*3+1], w2 = W_enc[f*3+2];
  const int chunk = (N + gridDim.x - 1) / gridDim.x;
  const int n0 = blockIdx.x * chunk;
  const int n1 = (n0 + chunk < N) ? (n0 + chunk) : N;
  float s = 0.f, q = 0.f;
  for (int n = n0; n < n1; n++){
    float x0 = x[n*3], x1 = x[n*3+1], x2 = x[n*3+2];
    float h = x0*w0 + x1*w1 + x2*w2;
    h0[(size_t)n*DD + f] = h;
    s += h; q += h*h;
  }
  atomicAdd(&stats[f], s);
  atomicAdd(&stats[DD+f], q);
}

// applies BN+ReLU; overwrites h0 in place with post-BN h (decoder term) + ph hi/lo
__global__ void k_enc_apply(float* __restrict__ h0, const float* __restrict__ gamma,
                            const float* __restrict__ beta, const float* __restrict__ stats,
                            unsigned short* __restrict__ ph_hi, unsigned short* __restrict__ ph_lo, int N){
  int idx = blockIdx.x*256 + threadIdx.x;
  if (idx >= N*DD) return;
  int f = idx & (DD-1);
  float invN = 1.f / (float)N;
  float mu = stats[f] * invN;
  float var = stats[DD+f] * invN - mu*mu;
  float v = (h0[idx] - mu) * rsqrtf(var + 1e-5f) * gamma[f] + beta[f];
  v = fmaxf(v, 0.f);
  h0[idx] = v;
  unsigned short hi, lo; bsplit(v, hi, lo);
  ph_hi[idx] = hi; ph_lo[idx] = lo;
}

// ---------- CSR build (1-level) ----------
__global__ void k_hist(const int* __restrict__ dst, int* __restrict__ counts, int E){
  int e = blockIdx.x*256 + threadIdx.x;
  if (e < E) atomicAdd(&counts[dst[e]], 1);
}

__global__ void __launch_bounds__(256) k_scan_part(const int* __restrict__ counts,
                                                   int* __restrict__ partials, int N){
  int i = blockIdx.x*256 + threadIdx.x;
  int v = (i < N) ? counts[i] : 0;
  #pragma unroll
  for (int off = 32; off > 0; off >>= 1) v += __shfl_down(v, off, 64);
  __shared__ int red[4];
  if ((threadIdx.x & 63) == 0) red[threadIdx.x >> 6] = v;
  __syncthreads();
  if (threadIdx.x == 0) partials[blockIdx.x] = red[0]+red[1]+red[2]+red[3];
}

__global__ void __launch_bounds__(256) k_scan_mid(int* __restrict__ partials, int P,
                                                  int* __restrict__ offsets, int N){
  __shared__ int lds[4];
  __shared__ int carry_s;
  const int lane = threadIdx.x & 63, wid = threadIdx.x >> 6;
  if (threadIdx.x == 0) carry_s = 0;
  __syncthreads();
  for (int base = 0; base < P; base += 256){
    int i = base + threadIdx.x;
    int v = (i < P) ? partials[i] : 0;
    int orig = v;
    #pragma unroll
    for (int off = 1; off < 64; off <<= 1){
      int u = __shfl_up(v, off, 64);
      if (lane >= off) v += u;
    }
    if (lane == 63) lds[wid] = v;
    __syncthreads();
    if (threadIdx.x == 0){
      int s = carry_s;
      for (int k = 0; k < 4; k++){ int t = lds[k]; lds[k] = s; s += t; }
      carry_s = s;
    }
    __syncthreads();
    int excl = v - orig + lds[wid];
    if (i < P) partials[i] = excl;
    __syncthreads();
  }
  if (threadIdx.x == 0) offsets[N] = carry_s;
}

__global__ void __launch_bounds__(256) k_scan_expand(const int* __restrict__ counts,
        const int* __restrict__ partials, int* __restrict__ offsets,
        int* __restrict__ cursors, int N){
  int i = blockIdx.x*256 + threadIdx.x;
  int v = (i < N) ? counts[i] : 0;
  int orig = v;
  const int lane = threadIdx.x & 63, wid = threadIdx.x >> 6;
  #pragma unroll
  for (int off = 1; off < 64; off <<= 1){
    int u = __shfl_up(v, off, 64);
    if (lane >= off) v += u;
  }
  __shared__ int lds[4];
  if (lane == 63) lds[wid] = v;
  __syncthreads();
  int wbase = 0;
  for (int k = 0; k < wid; k++) wbase += lds[k];
  int excl = partials[blockIdx.x] + wbase + v - orig;
  if (i < N){ offsets[i] = excl; cursors[i] = excl; }
}

__global__ void k_fill(const int* __restrict__ src, const int* __restrict__ dst,
                       const float* __restrict__ norm, int* __restrict__ cursors,
                       int* __restrict__ csr_src, float* __restrict__ csr_norm, int E){
  int e = blockIdx.x*256 + threadIdx.x;
  if (e >= E) return;
  int p = atomicAdd(&cursors[dst[e]], 1);
  csr_src[p] = src[e];
  csr_norm[p] = norm[e];
}

// ---------- fused layer: bf16 gather -> LDS -> MFMA -> gates ----------
// h lives ONLY as bf16 hi/lo (double-buffered). NO h_sum RMW: the gather result
// is written once (bf16-hi, write-only) to agg_out; the decoder sums them later.
// 256 threads. Phase1: 16 node-slots x 16 lanes x 2 passes.
// Phase2+3: wave w handles fg = 2w, 2w+1; A(agg) from LDS, A(ph) hi/lo global.
// LDS swizzle: 16B chunk c of row m at c^(m&7).
__global__ void __launch_bounds__(256, 4) k_layer(
        const unsigned short* __restrict__ phc_hi, const unsigned short* __restrict__ phc_lo,
        unsigned short* __restrict__ phn_hi, unsigned short* __restrict__ phn_lo,
        unsigned short* __restrict__ agg_out,
        const int* __restrict__ offsets, const int* __restrict__ csr_src,
        const float* __restrict__ csr_norm,
        const unsigned short* __restrict__ Wih_hi, const unsigned short* __restrict__ Wih_lo,
        const unsigned short* __restrict__ Whh_hi, const unsigned short* __restrict__ Whh_lo,
        const float* __restrict__ b_ih, const float* __restrict__ b_hh, int N){
  __shared__ unsigned short s_ah[32*DD];
  __shared__ unsigned short s_al[32*DD];
  const int tid = threadIdx.x;
  const int n0 = blockIdx.x * 32;

  // ---- phase 1: gather (bf16 rows) ----
  {
    const int slot = tid >> 4;   // node slot 0..15
    const int q    = tid & 15;   // feature octet
    #pragma unroll
    for (int pass = 0; pass < 2; pass++){
      const int m = slot + pass*16;
      const int n = n0 + m;
      float acc[8];
      #pragma unroll
      for (int t = 0; t < 8; t++) acc[t] = 0.f;
      if (n < N){
        const int s0 = offsets[n], s1 = offsets[n+1];
        int i = s0;
        for (; i + 8 <= s1; i += 8){
          int sE[8]; float wE[8]; bf16x8 R[8];
          #pragma unroll
          for (int u = 0; u < 8; u++){ sE[u] = csr_src[i+u]; wE[u] = csr_norm[i+u]; }
          #pragma unroll
          for (int u = 0; u < 8; u++) R[u] = *(const bf16x8*)(phc_hi + (size_t)sE[u]*DD + q*8);
          #pragma unroll
          for (int u = 0; u < 8; u++)
            #pragma unroll
            for (int t = 0; t < 8; t++)
              acc[t] = fmaf(wE[u], b2f((unsigned short)R[u][t]), acc[t]);
        }
        if (i + 4 <= s1){
          int sE[4]; float wE[4]; bf16x8 R[4];
          #pragma unroll
          for (int u = 0; u < 4; u++){ sE[u] = csr_src[i+u]; wE[u] = csr_norm[i+u]; }
          #pragma unroll
          for (int u = 0; u < 4; u++) R[u] = *(const bf16x8*)(phc_hi + (size_t)sE[u]*DD + q*8);
          #pragma unroll
          for (int u = 0; u < 4; u++)
            #pragma unroll
            for (int t = 0; t < 8; t++)
              acc[t] = fmaf(wE[u], b2f((unsigned short)R[u][t]), acc[t]);
          i += 4;
        }
        for (; i < s1; i++){
          int s = csr_src[i];
          float w = csr_norm[i];
          bf16x8 R = *(const bf16x8*)(phc_hi + (size_t)s*DD + q*8);
          #pragma unroll
          for (int t = 0; t < 8; t++)
            acc[t] = fmaf(w, b2f((unsigned short)R[t]), acc[t]);
        }
      }
      u16x8 vhi, vlo;
      #pragma unroll
      for (int t = 0; t < 8; t++){
        unsigned short hi, lo; bsplit(acc[t], hi, lo);
        vhi[t] = hi; vlo[t] = lo;
      }
      if (n < N)
        *(u16x8*)(agg_out + (size_t)n*DD + q*8) = vhi;   // write-only, for decoder
      const int cc = q ^ (m & 7);
      const int off = m*DD + cc*8;
      *(u16x8*)(s_ah + off) = vhi;
      *(u16x8*)(s_al + off) = vlo;
    }
  }
  __syncthreads();   // the only barrier: LDS A-frags ready

  // ---- phase 2+3 per feature group ----
  const int w = tid >> 6, l = tid & 63, ar = l & 15, aq = l >> 4;
  int r0 = n0 + ar;      if (r0 >= N) r0 = N-1;
  int r1 = n0 + 16 + ar; if (r1 >= N) r1 = N-1;
  const size_t p0 = (size_t)r0*DD + aq*8;
  const size_t p1 = (size_t)r1*DD + aq*8;
  const int sw = ar & 7;

  for (int g = 0; g < 2; g++){
    const int fg = w*2 + g;
    f32x4 acc_i[2][3], acc_h[2][3];
    #pragma unroll
    for (int ta = 0; ta < 2; ta++)
      #pragma unroll
      for (int t = 0; t < 3; t++){
        acc_i[ta][t] = (f32x4){0.f,0.f,0.f,0.f};
        acc_h[ta][t] = (f32x4){0.f,0.f,0.f,0.f};
      }

    #pragma unroll
    for (int ks = 0; ks < 4; ks++){
      const int c = (ks*4 + aq) ^ sw;
      bf16x8 ih0 = *(const bf16x8*)(s_ah + ar*DD       + c*8);
      bf16x8 ih1 = *(const bf16x8*)(s_ah + (16+ar)*DD  + c*8);
      bf16x8 il0 = *(const bf16x8*)(s_al + ar*DD       + c*8);
      bf16x8 il1 = *(const bf16x8*)(s_al + (16+ar)*DD  + c*8);
      bf16x8 hh0 = *(const bf16x8*)(phc_hi + p0 + ks*32);
      bf16x8 hh1 = *(const bf16x8*)(phc_hi + p1 + ks*32);
      bf16x8 hl0 = *(const bf16x8*)(phc_lo + p0 + ks*32);
      bf16x8 hl1 = *(const bf16x8*)(phc_lo + p1 + ks*32);
      #pragma unroll
      for (int t = 0; t < 3; t++){
        size_t bo = ((size_t)((fg*3 + t)*4 + ks)*64 + l)*8;
        bf16x8 bih = *(const bf16x8*)(Wih_hi + bo);
        bf16x8 bil = *(const bf16x8*)(Wih_lo + bo);
        bf16x8 bhh = *(const bf16x8*)(Whh_hi + bo);
        bf16x8 bhl = *(const bf16x8*)(Whh_lo + bo);
        acc_i[0][t] = __builtin_amdgcn_mfma_f32_16x16x32_bf16(ih0, bih, acc_i[0][t], 0, 0, 0);
        acc_i[0][t] = __builtin_amdgcn_mfma_f32_16x16x32_bf16(ih0, bil, acc_i[0][t], 0, 0, 0);
        acc_i[0][t] = __builtin_amdgcn_mfma_f32_16x16x32_bf16(il0, bih, acc_i[0][t], 0, 0, 0);
        acc_i[1][t] = __builtin_amdgcn_mfma_f32_16x16x32_bf16(ih1, bih, acc_i[1][t], 0, 0, 0);
        acc_i[1][t] = __builtin_amdgcn_mfma_f32_16x16x32_bf16(ih1, bil, acc_i[1][t], 0, 0, 0);
        acc_i[1][t] = __builtin_amdgcn_mfma_f32_16x16x32_bf16(il1, bih, acc_i[1][t], 0, 0, 0);
        acc_h[0][t] = __builtin_amdgcn_mfma_f32_16x16x32_bf16(hh0, bhh, acc_h[0][t], 0, 0, 0);
        acc_h[0][t] = __builtin_amdgcn_mfma_f32_16x16x32_bf16(hh0, bhl, acc_h[0][t], 0, 0, 0);
        acc_h[0][t] = __builtin_amdgcn_mfma_f32_16x16x32_bf16(hl0, bhh, acc_h[0][t], 0, 0, 0);
        acc_h[1][t] = __builtin_amdgcn_mfma_f32_16x16x32_bf16(hh1, bhh, acc_h[1][t], 0, 0, 0);
        acc_h[1][t] = __builtin_amdgcn_mfma_f32_16x16x32_bf16(hh1, bhl, acc_h[1][t], 0, 0, 0);
        acc_h[1][t] = __builtin_amdgcn_mfma_f32_16x16x32_bf16(hl1, bhh, acc_h[1][t], 0, 0, 0);
      }
    }

    const int f = fg*16 + ar;
    const float bir = b_ih[f], biz = b_ih[128+f], bin_ = b_ih[256+f];
    const float bhr = b_hh[f], bhz = b_hh[128+f], bhn = b_hh[256+f];
    #pragma unroll
    for (int ta = 0; ta < 2; ta++){
      #pragma unroll
      for (int r = 0; r < 4; r++){
        int n = n0 + ta*16 + aq*4 + r;
        if (n < N){
          float sir = acc_i[ta][0][r] + bir, shr = acc_h[ta][0][r] + bhr;
          float siz = acc_i[ta][1][r] + biz, shz = acc_h[ta][1][r] + bhz;
          float sin_ = acc_i[ta][2][r] + bin_, shn = acc_h[ta][2][r] + bhn;
          float rr = sigmoidf_(sir + shr);
          float zz = sigmoidf_(siz + shz);
          float nn = tanhf_(sin_ + rr*shn);
          size_t o = (size_t)n*DD + f;
          float hp = b2f(phc_hi[o]) + b2f(phc_lo[o]);
          float h = (1.f - zz)*nn + zz*hp;
          unsigned short hi, lo; bsplit(h, hi, lo);
          phn_hi[o] = hi; phn_lo[o] = lo;
        }
      }
    }
  }
}

// ---------- decoder stage 1: z = (h_bn + sum_l agg_l)/6 on the fly, matvec, stats ----------
__global__ void __launch_bounds__(256) k_dec1(const float* __restrict__ hbn,
        const unsigned short* __restrict__ aggs, size_t NF,
        const float* __restrict__ Wt_dec, float* __restrict__ y1,
        float* __restrict__ stats_d, int N){
  const int j = threadIdx.x & 63;
  const int slot = threadIdx.x >> 6;
  __shared__ float zs[4][DD];
  float s = 0.f, q = 0.f;
  const int stride = gridDim.x*4;
  for (int base = blockIdx.x*4; base < N; base += stride){
    const int n = base + slot;
    if (n < N){
      size_t o = (size_t)n*DD;
      float z0 = hbn[o + j], z1 = hbn[o + 64 + j];
      #pragma unroll
      for (int l = 0; l < 5; l++){
        z0 += b2f(aggs[l*NF + o + j]);
        z1 += b2f(aggs[l*NF + o + 64 + j]);
      }
      zs[slot][j]      = z0 * (1.f/6.f);
      zs[slot][64 + j] = z1 * (1.f/6.f);
    }
    __syncthreads();
    if (n < N){
      float acc = 0.f;
      for (int k = 0; k < DD; k += 4){
        float4 wv = *(const float4*)(Wt_dec + ((size_t)(k>>2)*64 + j)*4);
        acc += zs[slot][k]*wv.x + zs[slot][k+1]*wv.y + zs[slot][k+2]*wv.z + zs[slot][k+3]*wv.w;
      }
      y1[(size_t)n*64 + j] = acc;
      s += acc; q += acc*acc;
    }
    __syncthreads();
  }
  __shared__ float red[2][4][64];
  red[0][slot][j] = s; red[1][slot][j] = q;
  __syncthreads();
  if (slot == 0){
    s = red[0][0][j] + red[0][1][j] + red[0][2][j] + red[0][3][j];
    q = red[1][0][j] + red[1][1][j] + red[1][2][j] + red[1][3][j];
    float* st = stats_d + (size_t)(blockIdx.x & 7)*128;
    atomicAdd(&st[j], s);
    atomicAdd(&st[64+j], q);
  }
}

// ---------- decoder stage 2: sum stats copies, bn + relu + dot ----------
__global__ void __launch_bounds__(256) k_dec2(const float* __restrict__ y1,
        const float* __restrict__ gamma, const float* __restrict__ beta,
        const float* __restrict__ W_dec2, const float* __restrict__ stats_d,
        float* __restrict__ out, int N){
  const int j = threadIdx.x & 63;
  const int g = threadIdx.x >> 6;
  const int n = blockIdx.x*4 + g;
  if (n >= N) return;
  float ssum = 0.f, qsum = 0.f;
  #pragma unroll
  for (int c = 0; c < 8; c++){
    ssum += stats_d[c*128 + j];
    qsum += stats_d[c*128 + 64 + j];
  }
  float invN = 1.f / (float)N;
  float mu = ssum * invN;
  float var = qsum * invN - mu*mu;
  float v = (y1[(size_t)n*64 + j] - mu) * rsqrtf(var + 1e-5f) * gamma[j] + beta[j];
  v = fmaxf(v, 0.f) * W_dec2[j];
  for (int off = 32; off > 0; off >>= 1) v += __shfl_down(v, off, 64);
  if (j == 0) out[n] = v;
}

extern "C" void kernel_launch(void* const* d_in, const int* in_sizes, int n_in,
                              void* d_out, int out_size, void* d_ws, size_t ws_size,
                              hipStream_t stream) {
  const int N = in_sizes[0] / 3;
  const int E = in_sizes[1] / 2;
  const int P = (N + 255) / 256;

  const float* x     = (const float*)d_in[0];
  const int*   ei    = (const int*)d_in[1];
  const int*   src   = ei;
  const int*   dst   = ei + E;
  const float* norm  = (const float*)d_in[2];
  const float* W_enc = (const float*)d_in[3];
  const float* g_e   = (const float*)d_in[4];
  const float* b_e   = (const float*)d_in[5];
  const float* W_ih  = (const float*)d_in[6];
  const float* W_hh  = (const float*)d_in[7];
  const float* b_ih  = (const float*)d_in[8];
  const float* b_hh  = (const float*)d_in[9];
  const float* W_dec = (const float*)d_in[10];
  const float* g_d   = (const float*)d_in[11];
  const float* b_d   = (const float*)d_in[12];
  const float* W_dec2= (const float*)d_in[13];
  float* out = (float*)d_out;

  float* ws = (float*)d_ws;
  const size_t NF = (size_t)N * DD;
  float* scr    = ws;                        // NF fp32: raw h0 -> post-BN h (persists to k_dec1)
  float* stats  = scr + NF;                  // 256 enc + 1024 dec
  float* Wt_dec = stats + 1280;              // 64*128
  unsigned short* Wih_hi = (unsigned short*)(Wt_dec + 64*128);
  unsigned short* Wih_lo = Wih_hi + 384*128;
  unsigned short* Whh_hi = Wih_lo + 384*128;
  unsigned short* Whh_lo = Whh_hi + 384*128;
  unsigned short* ph_hiA = Whh_lo + 384*128; // NF ushorts each
  unsigned short* ph_loA = ph_hiA + NF;
  unsigned short* ph_hiB = ph_loA + NF;
  unsigned short* ph_loB = ph_hiB + NF;
  unsigned short* aggs   = ph_loB + NF;      // 5 * NF ushorts (per-layer gather results)
  int*   counts  = (int*)(aggs + 5*NF);      // N
  int*   offsets = counts + N;               // N+1
  int*   cursors = offsets + N + 1;          // N
  int*   partials= cursors + N;              // P
  int*   csr_src = partials + P;             // E
  float* csr_norm = (float*)(csr_src + E);   // E
  float* y1 = (float*)ph_hiA;                // N*64 fp32 overlays ph_hiA (ph dead at decode)

  hipMemsetAsync(stats, 0, 1280*sizeof(float), stream);
  hipMemsetAsync(counts, 0, (size_t)N*sizeof(int), stream);

  k_prep_frag<<<(2*384*128 + 64*128 + 255)/256, 256, 0, stream>>>(
      W_ih, W_hh, W_dec, Wih_hi, Wih_lo, Whh_hi, Whh_lo, Wt_dec);
  k_enc<<<256, 128, 0, stream>>>(x, W_enc, scr, stats, N);
  k_enc_apply<<<(N*DD + 255)/256, 256, 0, stream>>>(scr, g_e, b_e, stats, ph_hiA, ph_loA, N);

  k_hist<<<(E + 255)/256, 256, 0, stream>>>(dst, counts, E);
  k_scan_part<<<P, 256, 0, stream>>>(counts, partials, N);
  k_scan_mid<<<1, 256, 0, stream>>>(partials, P, offsets, N);
  k_scan_expand<<<P, 256, 0, stream>>>(counts, partials, offsets, cursors, N);
  k_fill<<<(E + 255)/256, 256, 0, stream>>>(src, dst, norm, cursors, csr_src, csr_norm, E);

  unsigned short* phh_c = ph_hiA; unsigned short* phl_c = ph_loA;
  unsigned short* phh_n = ph_hiB; unsigned short* phl_n = ph_loB;
  for (int l = 0; l < 5; l++){
    k_layer<<<(N + 31)/32, 256, 0, stream>>>(phh_c, phl_c, phh_n, phl_n, aggs + (size_t)l*NF,
                                             offsets, csr_src, csr_norm,
                                             Wih_hi, Wih_lo, Whh_hi, Whh_lo, b_ih, b_hh, N);
    { unsigned short* t = phh_c; phh_c = phh_n; phh_n = t; }
    { unsigned short* t = phl_c; phl_c = phl_n; phl_n = t; }
  }

  k_dec1<<<1024, 256, 0, stream>>>(scr, aggs, NF, Wt_dec, y1, stats + 256, N);
  k_dec2<<<(N + 3)/4, 256, 0, stream>>>(y1, g_d, b_d, W_dec2, stats + 256, out, N);
}

// Round 10
// 639.658 us; speedup vs baseline: 1.1893x; 1.1211x over previous
//
#include <hip/hip_runtime.h>
#include <hip/hip_bf16.h>

#define DD 128

typedef short bf16x8 __attribute__((ext_vector_type(8)));
typedef unsigned short u16x8 __attribute__((ext_vector_type(8)));
typedef float f32x4 __attribute__((ext_vector_type(4)));

__device__ __forceinline__ float sigmoidf_(float v){ return 1.f/(1.f+__expf(-v)); }
__device__ __forceinline__ float tanhf_(float v){
  float e2 = __expf(2.f*v);
  return 1.f - 2.f/(e2 + 1.f);
}
__device__ __forceinline__ float b2f(unsigned short u){
  unsigned int x = ((unsigned int)u) << 16;
  union { unsigned int i; float f; } c; c.i = x; return c.f;
}
__device__ __forceinline__ void bsplit(float v, unsigned short& hi, unsigned short& lo){
  __hip_bfloat16 h = __float2bfloat16(v);
  float hf = __bfloat162float(h);
  __hip_bfloat16 l = __float2bfloat16(v - hf);
  hi = *(unsigned short*)&h;
  lo = *(unsigned short*)&l;
}

// ---------- fused pre-pass 1: weight prep  ∪  encoder matvec+stats  ∪  dst histogram ----------
// prep: blocks [0, PREP_B); enc: [PREP_B, PREP_B+256); hist: rest.
#define PREP_B 416   // (2*384*128 + 64*128)/256
__global__ void __launch_bounds__(256) k_pre1(
        const float* __restrict__ W_ih, const float* __restrict__ W_hh,
        const float* __restrict__ W_dec, const float* __restrict__ x,
        const float* __restrict__ W_enc, const int* __restrict__ dst,
        unsigned short* __restrict__ Wih_hi, unsigned short* __restrict__ Wih_lo,
        unsigned short* __restrict__ Whh_hi, unsigned short* __restrict__ Whh_lo,
        float* __restrict__ Wt_dec, float* __restrict__ h0, float* __restrict__ stats,
        int* __restrict__ counts, int N, int E){
  const int tid = threadIdx.x;
  const int gb = blockIdx.x;
  const int TOT = 384*128;
  if (gb < PREP_B){
    int idx = gb*256 + tid;
    if (idx < 2*TOT){
      const float* W = (idx < TOT) ? W_ih : W_hh;
      unsigned short* Dh = (idx < TOT) ? Wih_hi : Whh_hi;
      unsigned short* Dl = (idx < TOT) ? Wih_lo : Whh_lo;
      int fi = (idx < TOT) ? idx : idx - TOT;
      int t = fi & 7;
      int l = (fi >> 3) & 63;
      int ks = (fi >> 9) & 3;
      int nt = fi >> 11;
      int fg = nt / 3, gate = nt % 3;
      int j = gate*128 + fg*16 + (l & 15);
      int k = ks*32 + ((l >> 4) & 3)*8 + t;
      unsigned short hi, lo;
      bsplit(W[j*128 + k], hi, lo);
      Dh[fi] = hi; Dl[fi] = lo;
    } else if (idx < 2*TOT + 64*128){
      int t2 = idx - 2*TOT;
      int j = t2 / 128, k = t2 % 128;
      int o = ((k>>2)*64 + j)*4 + (k&3);
      Wt_dec[o] = W_dec[t2];
    }
  } else if (gb < PREP_B + 256){
    const int b = gb - PREP_B;
    const int f = tid & 127;
    const int sub = tid >> 7;
    const float w0 = W_enc[f*3], w1 = W_enc[f*3+1], w2 = W_enc[f*3+2];
    const int chunk = (N + 255) / 256;
    const int n0 = b * chunk;
    const int n1 = (n0 + chunk < N) ? (n0 + chunk) : N;
    float s = 0.f, q = 0.f;
    for (int n = n0 + sub; n < n1; n += 2){
      float x0 = x[n*3], x1 = x[n*3+1], x2 = x[n*3+2];
      float h = x0*w0 + x1*w1 + x2*w2;
      h0[(size_t)n*DD + f] = h;
      s += h; q += h*h;
    }
    atomicAdd(&stats[f], s);
    atomicAdd(&stats[DD+f], q);
  } else {
    int e = (gb - PREP_B - 256)*256 + tid;
    if (e < E) atomicAdd(&counts[dst[e]], 1);
  }
}

// ---------- scan chain ----------
__global__ void __launch_bounds__(256) k_scan_part(const int* __restrict__ counts,
                                                   int* __restrict__ partials, int N){
  int i = blockIdx.x*256 + threadIdx.x;
  int v = (i < N) ? counts[i] : 0;
  #pragma unroll
  for (int off = 32; off > 0; off >>= 1) v += __shfl_down(v, off, 64);
  __shared__ int red[4];
  if ((threadIdx.x & 63) == 0) red[threadIdx.x >> 6] = v;
  __syncthreads();
  if (threadIdx.x == 0) partials[blockIdx.x] = red[0]+red[1]+red[2]+red[3];
}

__global__ void __launch_bounds__(256) k_scan_mid(int* __restrict__ partials, int P,
                                                  int* __restrict__ offsets, int N){
  __shared__ int lds[4];
  __shared__ int carry_s;
  const int lane = threadIdx.x & 63, wid = threadIdx.x >> 6;
  if (threadIdx.x == 0) carry_s = 0;
  __syncthreads();
  for (int base = 0; base < P; base += 256){
    int i = base + threadIdx.x;
    int v = (i < P) ? partials[i] : 0;
    int orig = v;
    #pragma unroll
    for (int off = 1; off < 64; off <<= 1){
      int u = __shfl_up(v, off, 64);
      if (lane >= off) v += u;
    }
    if (lane == 63) lds[wid] = v;
    __syncthreads();
    if (threadIdx.x == 0){
      int s = carry_s;
      for (int k = 0; k < 4; k++){ int t = lds[k]; lds[k] = s; s += t; }
      carry_s = s;
    }
    __syncthreads();
    int excl = v - orig + lds[wid];
    if (i < P) partials[i] = excl;
    __syncthreads();
  }
  if (threadIdx.x == 0) offsets[N] = carry_s;
}

__global__ void __launch_bounds__(256) k_scan_expand(const int* __restrict__ counts,
        const int* __restrict__ partials, int* __restrict__ offsets,
        int* __restrict__ cursors, int N){
  int i = blockIdx.x*256 + threadIdx.x;
  int v = (i < N) ? counts[i] : 0;
  int orig = v;
  const int lane = threadIdx.x & 63, wid = threadIdx.x >> 6;
  #pragma unroll
  for (int off = 1; off < 64; off <<= 1){
    int u = __shfl_up(v, off, 64);
    if (lane >= off) v += u;
  }
  __shared__ int lds[4];
  if (lane == 63) lds[wid] = v;
  __syncthreads();
  int wbase = 0;
  for (int k = 0; k < wid; k++) wbase += lds[k];
  int excl = partials[blockIdx.x] + wbase + v - orig;
  if (i < N){ offsets[i] = excl; cursors[i] = excl; }
}

// ---------- fused pre-pass 2: BN+ReLU apply  ∪  CSR fill ----------
__global__ void __launch_bounds__(256) k_pre2(
        const float* __restrict__ h0, const float* __restrict__ gamma,
        const float* __restrict__ beta, const float* __restrict__ stats,
        unsigned short* __restrict__ ph_hi, unsigned short* __restrict__ ph_lo,
        unsigned short* __restrict__ hbn_bf,
        const int* __restrict__ src, const int* __restrict__ dst,
        const float* __restrict__ norm, int* __restrict__ cursors,
        int2* __restrict__ csr, int N, int E, int AB){
  const int tid = threadIdx.x;
  if ((int)blockIdx.x < AB){
    int idx = blockIdx.x*256 + tid;
    if (idx >= N*DD) return;
    int f = idx & (DD-1);
    float invN = 1.f / (float)N;
    float mu = stats[f] * invN;
    float var = stats[DD+f] * invN - mu*mu;
    float v = (h0[idx] - mu) * rsqrtf(var + 1e-5f) * gamma[f] + beta[f];
    v = fmaxf(v, 0.f);
    unsigned short hi, lo; bsplit(v, hi, lo);
    ph_hi[idx] = hi; ph_lo[idx] = lo;
    hbn_bf[idx] = hi;
  } else {
    int e = ((int)blockIdx.x - AB)*256 + tid;
    if (e >= E) return;
    int p = atomicAdd(&cursors[dst[e]], 1);
    union { float f; int i; } c; c.f = norm[e];
    csr[p] = make_int2(src[e], c.i);
  }
}

// ---------- fused layer: bf16 gather -> LDS -> MFMA -> gates (layers 0..3) ----------
__global__ void __launch_bounds__(256, 4) k_layer(
        const unsigned short* __restrict__ phc_hi, const unsigned short* __restrict__ phc_lo,
        unsigned short* __restrict__ phn_hi, unsigned short* __restrict__ phn_lo,
        unsigned short* __restrict__ agg_out,
        const int* __restrict__ offsets, const int2* __restrict__ csr,
        const unsigned short* __restrict__ Wih_hi, const unsigned short* __restrict__ Wih_lo,
        const unsigned short* __restrict__ Whh_hi, const unsigned short* __restrict__ Whh_lo,
        const float* __restrict__ b_ih, const float* __restrict__ b_hh, int N){
  __shared__ unsigned short s_ah[32*DD];
  __shared__ unsigned short s_al[32*DD];
  const int tid = threadIdx.x;
  const int n0 = blockIdx.x * 32;

  // ---- phase 1: gather (bf16 rows) ----
  {
    const int slot = tid >> 4;   // node slot 0..15
    const int q    = tid & 15;   // feature octet
    #pragma unroll
    for (int pass = 0; pass < 2; pass++){
      const int m = slot + pass*16;
      const int n = n0 + m;
      float acc[8];
      #pragma unroll
      for (int t = 0; t < 8; t++) acc[t] = 0.f;
      if (n < N){
        const int s0 = offsets[n], s1 = offsets[n+1];
        int i = s0;
        for (; i + 8 <= s1; i += 8){
          int2 ed[8]; bf16x8 R[8];
          #pragma unroll
          for (int u = 0; u < 8; u++) ed[u] = csr[i+u];
          #pragma unroll
          for (int u = 0; u < 8; u++) R[u] = *(const bf16x8*)(phc_hi + (size_t)ed[u].x*DD + q*8);
          #pragma unroll
          for (int u = 0; u < 8; u++){
            union { int i; float f; } c; c.i = ed[u].y;
            #pragma unroll
            for (int t = 0; t < 8; t++)
              acc[t] = fmaf(c.f, b2f((unsigned short)R[u][t]), acc[t]);
          }
        }
        if (i + 4 <= s1){
          int2 ed[4]; bf16x8 R[4];
          #pragma unroll
          for (int u = 0; u < 4; u++) ed[u] = csr[i+u];
          #pragma unroll
          for (int u = 0; u < 4; u++) R[u] = *(const bf16x8*)(phc_hi + (size_t)ed[u].x*DD + q*8);
          #pragma unroll
          for (int u = 0; u < 4; u++){
            union { int i; float f; } c; c.i = ed[u].y;
            #pragma unroll
            for (int t = 0; t < 8; t++)
              acc[t] = fmaf(c.f, b2f((unsigned short)R[u][t]), acc[t]);
          }
          i += 4;
        }
        for (; i < s1; i++){
          int2 ed = csr[i];
          union { int i; float f; } c; c.i = ed.y;
          bf16x8 R = *(const bf16x8*)(phc_hi + (size_t)ed.x*DD + q*8);
          #pragma unroll
          for (int t = 0; t < 8; t++)
            acc[t] = fmaf(c.f, b2f((unsigned short)R[t]), acc[t]);
        }
      }
      u16x8 vhi, vlo;
      #pragma unroll
      for (int t = 0; t < 8; t++){
        unsigned short hi, lo; bsplit(acc[t], hi, lo);
        vhi[t] = hi; vlo[t] = lo;
      }
      if (n < N)
        *(u16x8*)(agg_out + (size_t)n*DD + q*8) = vhi;   // write-only, for decoder
      const int cc = q ^ (m & 7);
      const int off = m*DD + cc*8;
      *(u16x8*)(s_ah + off) = vhi;
      *(u16x8*)(s_al + off) = vlo;
    }
  }
  __syncthreads();   // the only barrier: LDS A-frags ready

  // ---- phase 2+3 per feature group ----
  const int w = tid >> 6, l = tid & 63, ar = l & 15, aq = l >> 4;
  int r0 = n0 + ar;      if (r0 >= N) r0 = N-1;
  int r1 = n0 + 16 + ar; if (r1 >= N) r1 = N-1;
  const size_t p0 = (size_t)r0*DD + aq*8;
  const size_t p1 = (size_t)r1*DD + aq*8;
  const int sw = ar & 7;

  for (int g = 0; g < 2; g++){
    const int fg = w*2 + g;
    f32x4 acc_i[2][3], acc_h[2][3];
    #pragma unroll
    for (int ta = 0; ta < 2; ta++)
      #pragma unroll
      for (int t = 0; t < 3; t++){
        acc_i[ta][t] = (f32x4){0.f,0.f,0.f,0.f};
        acc_h[ta][t] = (f32x4){0.f,0.f,0.f,0.f};
      }

    #pragma unroll
    for (int ks = 0; ks < 4; ks++){
      const int c = (ks*4 + aq) ^ sw;
      bf16x8 ih0 = *(const bf16x8*)(s_ah + ar*DD       + c*8);
      bf16x8 ih1 = *(const bf16x8*)(s_ah + (16+ar)*DD  + c*8);
      bf16x8 il0 = *(const bf16x8*)(s_al + ar*DD       + c*8);
      bf16x8 il1 = *(const bf16x8*)(s_al + (16+ar)*DD  + c*8);
      bf16x8 hh0 = *(const bf16x8*)(phc_hi + p0 + ks*32);
      bf16x8 hh1 = *(const bf16x8*)(phc_hi + p1 + ks*32);
      bf16x8 hl0 = *(const bf16x8*)(phc_lo + p0 + ks*32);
      bf16x8 hl1 = *(const bf16x8*)(phc_lo + p1 + ks*32);
      #pragma unroll
      for (int t = 0; t < 3; t++){
        size_t bo = ((size_t)((fg*3 + t)*4 + ks)*64 + l)*8;
        bf16x8 bih = *(const bf16x8*)(Wih_hi + bo);
        bf16x8 bil = *(const bf16x8*)(Wih_lo + bo);
        bf16x8 bhh = *(const bf16x8*)(Whh_hi + bo);
        bf16x8 bhl = *(const bf16x8*)(Whh_lo + bo);
        acc_i[0][t] = __builtin_amdgcn_mfma_f32_16x16x32_bf16(ih0, bih, acc_i[0][t], 0, 0, 0);
        acc_i[0][t] = __builtin_amdgcn_mfma_f32_16x16x32_bf16(ih0, bil, acc_i[0][t], 0, 0, 0);
        acc_i[0][t] = __builtin_amdgcn_mfma_f32_16x16x32_bf16(il0, bih, acc_i[0][t], 0, 0, 0);
        acc_i[1][t] = __builtin_amdgcn_mfma_f32_16x16x32_bf16(ih1, bih, acc_i[1][t], 0, 0, 0);
        acc_i[1][t] = __builtin_amdgcn_mfma_f32_16x16x32_bf16(ih1, bil, acc_i[1][t], 0, 0, 0);
        acc_i[1][t] = __builtin_amdgcn_mfma_f32_16x16x32_bf16(il1, bih, acc_i[1][t], 0, 0, 0);
        acc_h[0][t] = __builtin_amdgcn_mfma_f32_16x16x32_bf16(hh0, bhh, acc_h[0][t], 0, 0, 0);
        acc_h[0][t] = __builtin_amdgcn_mfma_f32_16x16x32_bf16(hh0, bhl, acc_h[0][t], 0, 0, 0);
        acc_h[0][t] = __builtin_amdgcn_mfma_f32_16x16x32_bf16(hl0, bhh, acc_h[0][t], 0, 0, 0);
        acc_h[1][t] = __builtin_amdgcn_mfma_f32_16x16x32_bf16(hh1, bhh, acc_h[1][t], 0, 0, 0);
        acc_h[1][t] = __builtin_amdgcn_mfma_f32_16x16x32_bf16(hh1, bhl, acc_h[1][t], 0, 0, 0);
        acc_h[1][t] = __builtin_amdgcn_mfma_f32_16x16x32_bf16(hl1, bhh, acc_h[1][t], 0, 0, 0);
      }
    }

    const int f = fg*16 + ar;
    const float bir = b_ih[f], biz = b_ih[128+f], bin_ = b_ih[256+f];
    const float bhr = b_hh[f], bhz = b_hh[128+f], bhn = b_hh[256+f];
    #pragma unroll
    for (int ta = 0; ta < 2; ta++){
      #pragma unroll
      for (int r = 0; r < 4; r++){
        int n = n0 + ta*16 + aq*4 + r;
        if (n < N){
          float sir = acc_i[ta][0][r] + bir, shr = acc_h[ta][0][r] + bhr;
          float siz = acc_i[ta][1][r] + biz, shz = acc_h[ta][1][r] + bhz;
          float sin_ = acc_i[ta][2][r] + bin_, shn = acc_h[ta][2][r] + bhn;
          float rr = sigmoidf_(sir + shr);
          float zz = sigmoidf_(siz + shz);
          float nn = tanhf_(sin_ + rr*shn);
          size_t o = (size_t)n*DD + f;
          float hp = b2f(phc_hi[o]) + b2f(phc_lo[o]);
          float h = (1.f - zz)*nn + zz*hp;
          unsigned short hi, lo; bsplit(h, hi, lo);
          phn_hi[o] = hi; phn_lo[o] = lo;
        }
      }
    }
  }
}

// ---------- layer 5: gather only (its GRU output is never consumed) ----------
__global__ void __launch_bounds__(256) k_agg_last(
        const unsigned short* __restrict__ phc_hi,
        unsigned short* __restrict__ agg_out,
        const int* __restrict__ offsets, const int2* __restrict__ csr, int N){
  const int slot = threadIdx.x >> 4;
  const int q    = threadIdx.x & 15;
  #pragma unroll
  for (int pass = 0; pass < 2; pass++){
    const int n = blockIdx.x*32 + slot + pass*16;
    if (n >= N) continue;
    float acc[8];
    #pragma unroll
    for (int t = 0; t < 8; t++) acc[t] = 0.f;
    const int s0 = offsets[n], s1 = offsets[n+1];
    int i = s0;
    for (; i + 8 <= s1; i += 8){
      int2 ed[8]; bf16x8 R[8];
      #pragma unroll
      for (int u = 0; u < 8; u++) ed[u] = csr[i+u];
      #pragma unroll
      for (int u = 0; u < 8; u++) R[u] = *(const bf16x8*)(phc_hi + (size_t)ed[u].x*DD + q*8);
      #pragma unroll
      for (int u = 0; u < 8; u++){
        union { int i; float f; } c; c.i = ed[u].y;
        #pragma unroll
        for (int t = 0; t < 8; t++)
          acc[t] = fmaf(c.f, b2f((unsigned short)R[u][t]), acc[t]);
      }
    }
    for (; i < s1; i++){
      int2 ed = csr[i];
      union { int i; float f; } c; c.i = ed.y;
      bf16x8 R = *(const bf16x8*)(phc_hi + (size_t)ed.x*DD + q*8);
      #pragma unroll
      for (int t = 0; t < 8; t++)
        acc[t] = fmaf(c.f, b2f((unsigned short)R[t]), acc[t]);
    }
    u16x8 vhi;
    #pragma unroll
    for (int t = 0; t < 8; t++){
      __hip_bfloat16 h = __float2bfloat16(acc[t]);
      vhi[t] = *(unsigned short*)&h;
    }
    *(u16x8*)(agg_out + (size_t)n*DD + q*8) = vhi;
  }
}

// ---------- decoder stage 1: z = (hbn + sum_l agg_l)/6 on the fly, matvec, stats ----------
__global__ void __launch_bounds__(256) k_dec1(const unsigned short* __restrict__ hbn,
        const unsigned short* __restrict__ aggs, size_t NF,
        const float* __restrict__ Wt_dec, float* __restrict__ y1,
        float* __restrict__ stats_d, int N){
  const int j = threadIdx.x & 63;
  const int slot = threadIdx.x >> 6;
  __shared__ float zs[4][DD];
  float s = 0.f, q = 0.f;
  const int stride = gridDim.x*4;
  for (int base = blockIdx.x*4; base < N; base += stride){
    const int n = base + slot;
    if (n < N){
      size_t o = (size_t)n*DD;
      float z0 = b2f(hbn[o + j]), z1 = b2f(hbn[o + 64 + j]);
      #pragma unroll
      for (int l = 0; l < 5; l++){
        z0 += b2f(aggs[l*NF + o + j]);
        z1 += b2f(aggs[l*NF + o + 64 + j]);
      }
      zs[slot][j]      = z0 * (1.f/6.f);
      zs[slot][64 + j] = z1 * (1.f/6.f);
    }
    __syncthreads();
    if (n < N){
      float acc = 0.f;
      for (int k = 0; k < DD; k += 4){
        float4 wv = *(const float4*)(Wt_dec + ((size_t)(k>>2)*64 + j)*4);
        acc += zs[slot][k]*wv.x + zs[slot][k+1]*wv.y + zs[slot][k+2]*wv.z + zs[slot][k+3]*wv.w;
      }
      y1[(size_t)n*64 + j] = acc;
      s += acc; q += acc*acc;
    }
    __syncthreads();
  }
  __shared__ float red[2][4][64];
  red[0][slot][j] = s; red[1][slot][j] = q;
  __syncthreads();
  if (slot == 0){
    s = red[0][0][j] + red[0][1][j] + red[0][2][j] + red[0][3][j];
    q = red[1][0][j] + red[1][1][j] + red[1][2][j] + red[1][3][j];
    float* st = stats_d + (size_t)(blockIdx.x & 7)*128;
    atomicAdd(&st[j], s);
    atomicAdd(&st[64+j], q);
  }
}

// ---------- decoder stage 2: sum stats copies, bn + relu + dot ----------
__global__ void __launch_bounds__(256) k_dec2(const float* __restrict__ y1,
        const float* __restrict__ gamma, const float* __restrict__ beta,
        const float* __restrict__ W_dec2, const float* __restrict__ stats_d,
        float* __restrict__ out, int N){
  const int j = threadIdx.x & 63;
  const int g = threadIdx.x >> 6;
  const int n = blockIdx.x*4 + g;
  if (n >= N) return;
  float ssum = 0.f, qsum = 0.f;
  #pragma unroll
  for (int c = 0; c < 8; c++){
    ssum += stats_d[c*128 + j];
    qsum += stats_d[c*128 + 64 + j];
  }
  float invN = 1.f / (float)N;
  float mu = ssum * invN;
  float var = qsum * invN - mu*mu;
  float v = (y1[(size_t)n*64 + j] - mu) * rsqrtf(var + 1e-5f) * gamma[j] + beta[j];
  v = fmaxf(v, 0.f) * W_dec2[j];
  for (int off = 32; off > 0; off >>= 1) v += __shfl_down(v, off, 64);
  if (j == 0) out[n] = v;
}

extern "C" void kernel_launch(void* const* d_in, const int* in_sizes, int n_in,
                              void* d_out, int out_size, void* d_ws, size_t ws_size,
                              hipStream_t stream) {
  const int N = in_sizes[0] / 3;
  const int E = in_sizes[1] / 2;
  const int P = (N + 255) / 256;
  const int HIST_B = (E + 255) / 256;
  const int AB = (N*DD + 255) / 256;

  const float* x     = (const float*)d_in[0];
  const int*   ei    = (const int*)d_in[1];
  const int*   src   = ei;
  const int*   dst   = ei + E;
  const float* norm  = (const float*)d_in[2];
  const float* W_enc = (const float*)d_in[3];
  const float* g_e   = (const float*)d_in[4];
  const float* b_e   = (const float*)d_in[5];
  const float* W_ih  = (const float*)d_in[6];
  const float* W_hh  = (const float*)d_in[7];
  const float* b_ih  = (const float*)d_in[8];
  const float* b_hh  = (const float*)d_in[9];
  const float* W_dec = (const float*)d_in[10];
  const float* g_d   = (const float*)d_in[11];
  const float* b_d   = (const float*)d_in[12];
  const float* W_dec2= (const float*)d_in[13];
  float* out = (float*)d_out;

  float* ws = (float*)d_ws;
  const size_t NF = (size_t)N * DD;
  float* scr    = ws;                        // NF fp32: raw h0 (enc -> enc_apply)
  float* stats  = scr + NF;                  // 256 enc + 1024 dec
  float* Wt_dec = stats + 1280;              // 64*128
  unsigned short* Wih_hi = (unsigned short*)(Wt_dec + 64*128);
  unsigned short* Wih_lo = Wih_hi + 384*128;
  unsigned short* Whh_hi = Wih_lo + 384*128;
  unsigned short* Whh_lo = Whh_hi + 384*128;
  unsigned short* ph_hiA = Whh_lo + 384*128; // NF ushorts each
  unsigned short* ph_loA = ph_hiA + NF;
  unsigned short* ph_hiB = ph_loA + NF;
  unsigned short* ph_loB = ph_hiB + NF;
  unsigned short* hbn_bf = ph_loB + NF;      // NF ushorts (post-BN h, decoder term)
  unsigned short* aggs   = hbn_bf + NF;      // 5 * NF ushorts
  int*   counts  = (int*)(aggs + 5*NF);      // N
  int*   offsets = counts + N;               // N+1
  int*   cursors = offsets + N + 1;          // N
  int*   partials= cursors + N;              // P
  int2*  csr     = (int2*)(partials + P);    // E int2 (src, norm-bits)
  float* y1 = (float*)ph_hiA;                // N*64 fp32 overlays ph_hiA (dead at decode)

  hipMemsetAsync(stats, 0, 1280*sizeof(float), stream);
  hipMemsetAsync(counts, 0, (size_t)N*sizeof(int), stream);

  k_pre1<<<PREP_B + 256 + HIST_B, 256, 0, stream>>>(
      W_ih, W_hh, W_dec, x, W_enc, dst,
      Wih_hi, Wih_lo, Whh_hi, Whh_lo, Wt_dec, scr, stats, counts, N, E);
  k_scan_part<<<P, 256, 0, stream>>>(counts, partials, N);
  k_scan_mid<<<1, 256, 0, stream>>>(partials, P, offsets, N);
  k_scan_expand<<<P, 256, 0, stream>>>(counts, partials, offsets, cursors, N);
  k_pre2<<<AB + HIST_B, 256, 0, stream>>>(
      scr, g_e, b_e, stats, ph_hiA, ph_loA, hbn_bf,
      src, dst, norm, cursors, csr, N, E, AB);

  unsigned short* phh_c = ph_hiA; unsigned short* phl_c = ph_loA;
  unsigned short* phh_n = ph_hiB; unsigned short* phl_n = ph_loB;
  for (int l = 0; l < 4; l++){
    k_layer<<<(N + 31)/32, 256, 0, stream>>>(phh_c, phl_c, phh_n, phl_n, aggs + (size_t)l*NF,
                                             offsets, csr,
                                             Wih_hi, Wih_lo, Whh_hi, Whh_lo, b_ih, b_hh, N);
    { unsigned short* t = phh_c; phh_c = phh_n; phh_n = t; }
    { unsigned short* t = phl_c; phl_c = phl_n; phl_n = t; }
  }
  k_agg_last<<<(N + 31)/32, 256, 0, stream>>>(phh_c, aggs + 4*NF, offsets, csr, N);

  k_dec1<<<1024, 256, 0, stream>>>(hbn_bf, aggs, NF, Wt_dec, y1, stats + 256, N);
  k_dec2<<<(N + 3)/4, 256, 0, stream>>>(y1, g_d, b_d, W_dec2, stats + 256, out, N);
}

// Round 11
// 605.938 us; speedup vs baseline: 1.2555x; 1.0556x over previous
//
#include <hip/hip_runtime.h>
#include <hip/hip_bf16.h>

#define DD 128

typedef short bf16x8 __attribute__((ext_vector_type(8)));
typedef unsigned short u16x8 __attribute__((ext_vector_type(8)));
typedef float f32x4 __attribute__((ext_vector_type(4)));

__device__ __forceinline__ float sigmoidf_(float v){ return 1.f/(1.f+__expf(-v)); }
__device__ __forceinline__ float tanhf_(float v){
  float e2 = __expf(2.f*v);
  return 1.f - 2.f/(e2 + 1.f);
}
__device__ __forceinline__ float b2f(unsigned short u){
  unsigned int x = ((unsigned int)u) << 16;
  union { unsigned int i; float f; } c; c.i = x; return c.f;
}
__device__ __forceinline__ void bsplit(float v, unsigned short& hi, unsigned short& lo){
  __hip_bfloat16 h = __float2bfloat16(v);
  float hf = __bfloat162float(h);
  __hip_bfloat16 l = __float2bfloat16(v - hf);
  hi = *(unsigned short*)&h;
  lo = *(unsigned short*)&l;
}
__device__ __forceinline__ unsigned short f2b(float v){
  __hip_bfloat16 h = __float2bfloat16(v);
  return *(unsigned short*)&h;
}

// ---------- fused pre-pass 1: weight prep  ∪  encoder matvec+stats  ∪  dst histogram ----------
#define PREP_B 416   // (2*384*128 + 64*128)/256
__global__ void __launch_bounds__(256) k_pre1(
        const float* __restrict__ W_ih, const float* __restrict__ W_hh,
        const float* __restrict__ W_dec, const float* __restrict__ x,
        const float* __restrict__ W_enc, const int* __restrict__ dst,
        unsigned short* __restrict__ Wih_hi, unsigned short* __restrict__ Wih_lo,
        unsigned short* __restrict__ Whh_hi, unsigned short* __restrict__ Whh_lo,
        float* __restrict__ Wt_dec, float* __restrict__ h0, float* __restrict__ stats,
        int* __restrict__ counts, int N, int E){
  const int tid = threadIdx.x;
  const int gb = blockIdx.x;
  const int TOT = 384*128;
  if (gb < PREP_B){
    int idx = gb*256 + tid;
    if (idx < 2*TOT){
      const float* W = (idx < TOT) ? W_ih : W_hh;
      unsigned short* Dh = (idx < TOT) ? Wih_hi : Whh_hi;
      unsigned short* Dl = (idx < TOT) ? Wih_lo : Whh_lo;
      int fi = (idx < TOT) ? idx : idx - TOT;
      int t = fi & 7;
      int l = (fi >> 3) & 63;
      int ks = (fi >> 9) & 3;
      int nt = fi >> 11;
      int fg = nt / 3, gate = nt % 3;
      int j = gate*128 + fg*16 + (l & 15);
      int k = ks*32 + ((l >> 4) & 3)*8 + t;
      unsigned short hi, lo;
      bsplit(W[j*128 + k], hi, lo);
      Dh[fi] = hi; Dl[fi] = lo;
    } else if (idx < 2*TOT + 64*128){
      int t2 = idx - 2*TOT;
      int j = t2 / 128, k = t2 % 128;
      int o = ((k>>2)*64 + j)*4 + (k&3);
      Wt_dec[o] = W_dec[t2];
    }
  } else if (gb < PREP_B + 256){
    const int b = gb - PREP_B;
    const int f = tid & 127;
    const int sub = tid >> 7;
    const float w0 = W_enc[f*3], w1 = W_enc[f*3+1], w2 = W_enc[f*3+2];
    const int chunk = (N + 255) / 256;
    const int n0 = b * chunk;
    const int n1 = (n0 + chunk < N) ? (n0 + chunk) : N;
    float s = 0.f, q = 0.f;
    for (int n = n0 + sub; n < n1; n += 2){
      float x0 = x[n*3], x1 = x[n*3+1], x2 = x[n*3+2];
      float h = x0*w0 + x1*w1 + x2*w2;
      h0[(size_t)n*DD + f] = h;
      s += h; q += h*h;
    }
    atomicAdd(&stats[f], s);
    atomicAdd(&stats[DD+f], q);
  } else {
    int e = (gb - PREP_B - 256)*256 + tid;
    if (e < E) atomicAdd(&counts[dst[e]], 1);
  }
}

// ---------- scan chain ----------
__global__ void __launch_bounds__(256) k_scan_part(const int* __restrict__ counts,
                                                   int* __restrict__ partials, int N){
  int i = blockIdx.x*256 + threadIdx.x;
  int v = (i < N) ? counts[i] : 0;
  #pragma unroll
  for (int off = 32; off > 0; off >>= 1) v += __shfl_down(v, off, 64);
  __shared__ int red[4];
  if ((threadIdx.x & 63) == 0) red[threadIdx.x >> 6] = v;
  __syncthreads();
  if (threadIdx.x == 0) partials[blockIdx.x] = red[0]+red[1]+red[2]+red[3];
}

__global__ void __launch_bounds__(256) k_scan_mid(int* __restrict__ partials, int P,
                                                  int* __restrict__ offsets, int N){
  __shared__ int lds[4];
  __shared__ int carry_s;
  const int lane = threadIdx.x & 63, wid = threadIdx.x >> 6;
  if (threadIdx.x == 0) carry_s = 0;
  __syncthreads();
  for (int base = 0; base < P; base += 256){
    int i = base + threadIdx.x;
    int v = (i < P) ? partials[i] : 0;
    int orig = v;
    #pragma unroll
    for (int off = 1; off < 64; off <<= 1){
      int u = __shfl_up(v, off, 64);
      if (lane >= off) v += u;
    }
    if (lane == 63) lds[wid] = v;
    __syncthreads();
    if (threadIdx.x == 0){
      int s = carry_s;
      for (int k = 0; k < 4; k++){ int t = lds[k]; lds[k] = s; s += t; }
      carry_s = s;
    }
    __syncthreads();
    int excl = v - orig + lds[wid];
    if (i < P) partials[i] = excl;
    __syncthreads();
  }
  if (threadIdx.x == 0) offsets[N] = carry_s;
}

__global__ void __launch_bounds__(256) k_scan_expand(const int* __restrict__ counts,
        const int* __restrict__ partials, int* __restrict__ offsets,
        int* __restrict__ cursors, int N){
  int i = blockIdx.x*256 + threadIdx.x;
  int v = (i < N) ? counts[i] : 0;
  int orig = v;
  const int lane = threadIdx.x & 63, wid = threadIdx.x >> 6;
  #pragma unroll
  for (int off = 1; off < 64; off <<= 1){
    int u = __shfl_up(v, off, 64);
    if (lane >= off) v += u;
  }
  __shared__ int lds[4];
  if (lane == 63) lds[wid] = v;
  __syncthreads();
  int wbase = 0;
  for (int k = 0; k < wid; k++) wbase += lds[k];
  int excl = partials[blockIdx.x] + wbase + v - orig;
  if (i < N){ offsets[i] = excl; cursors[i] = excl; }
}

// ---------- fused pre-pass 2: BN+ReLU apply  ∪  CSR fill ----------
__global__ void __launch_bounds__(256) k_pre2(
        const float* __restrict__ h0, const float* __restrict__ gamma,
        const float* __restrict__ beta, const float* __restrict__ stats,
        unsigned short* __restrict__ ph_hi, unsigned short* __restrict__ hbn_bf,
        const int* __restrict__ src, const int* __restrict__ dst,
        const float* __restrict__ norm, int* __restrict__ cursors,
        int2* __restrict__ csr, int N, int E, int AB){
  const int tid = threadIdx.x;
  if ((int)blockIdx.x < AB){
    int idx = blockIdx.x*256 + tid;
    if (idx >= N*DD) return;
    int f = idx & (DD-1);
    float invN = 1.f / (float)N;
    float mu = stats[f] * invN;
    float var = stats[DD+f] * invN - mu*mu;
    float v = (h0[idx] - mu) * rsqrtf(var + 1e-5f) * gamma[f] + beta[f];
    v = fmaxf(v, 0.f);
    unsigned short hi = f2b(v);
    ph_hi[idx] = hi;
    hbn_bf[idx] = hi;
  } else {
    int e = ((int)blockIdx.x - AB)*256 + tid;
    if (e >= E) return;
    int p = atomicAdd(&cursors[dst[e]], 1);
    union { float f; int i; } c; c.f = norm[e];
    csr[p] = make_int2(src[e], c.i);
  }
}

// ---------- fused layer (0..3): bf16 gather -> LDS -> MFMA -> gates ----------
// h carried as bf16-hi ONLY (double-buffered). agg written bf16-hi for decoder.
// i-path MFMA 3-term (agg hi/lo from LDS); h-path 2-term (h-hi x W hi/lo).
__global__ void __launch_bounds__(256, 4) k_layer(
        const unsigned short* __restrict__ phc_hi,
        unsigned short* __restrict__ phn_hi,
        unsigned short* __restrict__ agg_out,
        const int* __restrict__ offsets, const int2* __restrict__ csr,
        const unsigned short* __restrict__ Wih_hi, const unsigned short* __restrict__ Wih_lo,
        const unsigned short* __restrict__ Whh_hi, const unsigned short* __restrict__ Whh_lo,
        const float* __restrict__ b_ih, const float* __restrict__ b_hh, int N){
  __shared__ unsigned short s_ah[32*DD];
  __shared__ unsigned short s_al[32*DD];
  const int tid = threadIdx.x;
  const int n0 = blockIdx.x * 32;

  // ---- phase 1: gather (bf16 rows) ----
  {
    const int slot = tid >> 4;   // node slot 0..15
    const int q    = tid & 15;   // feature octet
    #pragma unroll
    for (int pass = 0; pass < 2; pass++){
      const int m = slot + pass*16;
      const int n = n0 + m;
      float acc[8];
      #pragma unroll
      for (int t = 0; t < 8; t++) acc[t] = 0.f;
      if (n < N){
        const int s0 = offsets[n], s1 = offsets[n+1];
        int i = s0;
        for (; i + 8 <= s1; i += 8){
          int2 ed[8]; bf16x8 R[8];
          #pragma unroll
          for (int u = 0; u < 8; u++) ed[u] = csr[i+u];
          #pragma unroll
          for (int u = 0; u < 8; u++) R[u] = *(const bf16x8*)(phc_hi + (size_t)ed[u].x*DD + q*8);
          #pragma unroll
          for (int u = 0; u < 8; u++){
            union { int i; float f; } c; c.i = ed[u].y;
            #pragma unroll
            for (int t = 0; t < 8; t++)
              acc[t] = fmaf(c.f, b2f((unsigned short)R[u][t]), acc[t]);
          }
        }
        if (i + 4 <= s1){
          int2 ed[4]; bf16x8 R[4];
          #pragma unroll
          for (int u = 0; u < 4; u++) ed[u] = csr[i+u];
          #pragma unroll
          for (int u = 0; u < 4; u++) R[u] = *(const bf16x8*)(phc_hi + (size_t)ed[u].x*DD + q*8);
          #pragma unroll
          for (int u = 0; u < 4; u++){
            union { int i; float f; } c; c.i = ed[u].y;
            #pragma unroll
            for (int t = 0; t < 8; t++)
              acc[t] = fmaf(c.f, b2f((unsigned short)R[u][t]), acc[t]);
          }
          i += 4;
        }
        for (; i < s1; i++){
          int2 ed = csr[i];
          union { int i; float f; } c; c.i = ed.y;
          bf16x8 R = *(const bf16x8*)(phc_hi + (size_t)ed.x*DD + q*8);
          #pragma unroll
          for (int t = 0; t < 8; t++)
            acc[t] = fmaf(c.f, b2f((unsigned short)R[t]), acc[t]);
        }
      }
      u16x8 vhi, vlo;
      #pragma unroll
      for (int t = 0; t < 8; t++){
        unsigned short hi, lo; bsplit(acc[t], hi, lo);
        vhi[t] = hi; vlo[t] = lo;
      }
      if (n < N)
        *(u16x8*)(agg_out + (size_t)n*DD + q*8) = vhi;   // write-only, for decoder
      const int cc = q ^ (m & 7);
      const int off = m*DD + cc*8;
      *(u16x8*)(s_ah + off) = vhi;
      *(u16x8*)(s_al + off) = vlo;
    }
  }
  __syncthreads();   // the only barrier: LDS A-frags ready

  // ---- phase 2+3 per feature group ----
  const int w = tid >> 6, l = tid & 63, ar = l & 15, aq = l >> 4;
  int r0 = n0 + ar;      if (r0 >= N) r0 = N-1;
  int r1 = n0 + 16 + ar; if (r1 >= N) r1 = N-1;
  const size_t p0 = (size_t)r0*DD + aq*8;
  const size_t p1 = (size_t)r1*DD + aq*8;
  const int sw = ar & 7;

  for (int g = 0; g < 2; g++){
    const int fg = w*2 + g;
    f32x4 acc_i[2][3], acc_h[2][3];
    #pragma unroll
    for (int ta = 0; ta < 2; ta++)
      #pragma unroll
      for (int t = 0; t < 3; t++){
        acc_i[ta][t] = (f32x4){0.f,0.f,0.f,0.f};
        acc_h[ta][t] = (f32x4){0.f,0.f,0.f,0.f};
      }

    #pragma unroll
    for (int ks = 0; ks < 4; ks++){
      const int c = (ks*4 + aq) ^ sw;
      bf16x8 ih0 = *(const bf16x8*)(s_ah + ar*DD       + c*8);
      bf16x8 ih1 = *(const bf16x8*)(s_ah + (16+ar)*DD  + c*8);
      bf16x8 il0 = *(const bf16x8*)(s_al + ar*DD       + c*8);
      bf16x8 il1 = *(const bf16x8*)(s_al + (16+ar)*DD  + c*8);
      bf16x8 hh0 = *(const bf16x8*)(phc_hi + p0 + ks*32);
      bf16x8 hh1 = *(const bf16x8*)(phc_hi + p1 + ks*32);
      #pragma unroll
      for (int t = 0; t < 3; t++){
        size_t bo = ((size_t)((fg*3 + t)*4 + ks)*64 + l)*8;
        bf16x8 bih = *(const bf16x8*)(Wih_hi + bo);
        bf16x8 bil = *(const bf16x8*)(Wih_lo + bo);
        bf16x8 bhh = *(const bf16x8*)(Whh_hi + bo);
        bf16x8 bhl = *(const bf16x8*)(Whh_lo + bo);
        acc_i[0][t] = __builtin_amdgcn_mfma_f32_16x16x32_bf16(ih0, bih, acc_i[0][t], 0, 0, 0);
        acc_i[0][t] = __builtin_amdgcn_mfma_f32_16x16x32_bf16(ih0, bil, acc_i[0][t], 0, 0, 0);
        acc_i[0][t] = __builtin_amdgcn_mfma_f32_16x16x32_bf16(il0, bih, acc_i[0][t], 0, 0, 0);
        acc_i[1][t] = __builtin_amdgcn_mfma_f32_16x16x32_bf16(ih1, bih, acc_i[1][t], 0, 0, 0);
        acc_i[1][t] = __builtin_amdgcn_mfma_f32_16x16x32_bf16(ih1, bil, acc_i[1][t], 0, 0, 0);
        acc_i[1][t] = __builtin_amdgcn_mfma_f32_16x16x32_bf16(il1, bih, acc_i[1][t], 0, 0, 0);
        acc_h[0][t] = __builtin_amdgcn_mfma_f32_16x16x32_bf16(hh0, bhh, acc_h[0][t], 0, 0, 0);
        acc_h[0][t] = __builtin_amdgcn_mfma_f32_16x16x32_bf16(hh0, bhl, acc_h[0][t], 0, 0, 0);
        acc_h[1][t] = __builtin_amdgcn_mfma_f32_16x16x32_bf16(hh1, bhh, acc_h[1][t], 0, 0, 0);
        acc_h[1][t] = __builtin_amdgcn_mfma_f32_16x16x32_bf16(hh1, bhl, acc_h[1][t], 0, 0, 0);
      }
    }

    const int f = fg*16 + ar;
    const float bir = b_ih[f], biz = b_ih[128+f], bin_ = b_ih[256+f];
    const float bhr = b_hh[f], bhz = b_hh[128+f], bhn = b_hh[256+f];
    #pragma unroll
    for (int ta = 0; ta < 2; ta++){
      #pragma unroll
      for (int r = 0; r < 4; r++){
        int n = n0 + ta*16 + aq*4 + r;
        if (n < N){
          float sir = acc_i[ta][0][r] + bir, shr = acc_h[ta][0][r] + bhr;
          float siz = acc_i[ta][1][r] + biz, shz = acc_h[ta][1][r] + bhz;
          float sin_ = acc_i[ta][2][r] + bin_, shn = acc_h[ta][2][r] + bhn;
          float rr = sigmoidf_(sir + shr);
          float zz = sigmoidf_(siz + shz);
          float nn = tanhf_(sin_ + rr*shn);
          size_t o = (size_t)n*DD + f;
          float hp = b2f(phc_hi[o]);
          float h = (1.f - zz)*nn + zz*hp;
          phn_hi[o] = f2b(h);
        }
      }
    }
  }
}

// ---------- decoder stage 1 (fused with layer-5 gather): ----------
// wave-per-node: z = (hbn + sum_{l<4} agg_l + live_gather(ph5))/6, matvec, stats.
__global__ void __launch_bounds__(256) k_dec1(const unsigned short* __restrict__ hbn,
        const unsigned short* __restrict__ aggs, size_t NF,
        const unsigned short* __restrict__ ph5,
        const int* __restrict__ offsets, const int2* __restrict__ csr,
        const float* __restrict__ Wt_dec, float* __restrict__ y1,
        float* __restrict__ stats_d, int N){
  const int j = threadIdx.x & 63;     // lane: output col / feature pair
  const int slot = threadIdx.x >> 6;  // wave: node slot
  __shared__ float zs[4][DD];
  float s = 0.f, q = 0.f;
  const int stride = gridDim.x*4;
  for (int base = blockIdx.x*4; base < N; base += stride){
    const int n = base + slot;
    if (n < N){
      size_t o = (size_t)n*DD + j*2;
      float z0, z1;
      { unsigned int u = *(const unsigned int*)(hbn + o);
        z0 = b2f((unsigned short)(u & 0xffff)); z1 = b2f((unsigned short)(u >> 16)); }
      #pragma unroll
      for (int l = 0; l < 4; l++){
        unsigned int u = *(const unsigned int*)(aggs + l*NF + o);
        z0 += b2f((unsigned short)(u & 0xffff)); z1 += b2f((unsigned short)(u >> 16));
      }
      // live layer-5 gather (each lane: 2 bf16 = 4B; wave covers the 256B row)
      const int s0 = offsets[n], s1 = offsets[n+1];
      int i = s0;
      for (; i + 8 <= s1; i += 8){
        int2 ed[8]; unsigned int R[8];
        #pragma unroll
        for (int u = 0; u < 8; u++) ed[u] = csr[i+u];
        #pragma unroll
        for (int u = 0; u < 8; u++) R[u] = *(const unsigned int*)(ph5 + (size_t)ed[u].x*DD + j*2);
        #pragma unroll
        for (int u = 0; u < 8; u++){
          union { int i; float f; } c; c.i = ed[u].y;
          z0 = fmaf(c.f, b2f((unsigned short)(R[u] & 0xffff)), z0);
          z1 = fmaf(c.f, b2f((unsigned short)(R[u] >> 16)), z1);
        }
      }
      for (; i < s1; i++){
        int2 ed = csr[i];
        union { int i; float f; } c; c.i = ed.y;
        unsigned int u = *(const unsigned int*)(ph5 + (size_t)ed.x*DD + j*2);
        z0 = fmaf(c.f, b2f((unsigned short)(u & 0xffff)), z0);
        z1 = fmaf(c.f, b2f((unsigned short)(u >> 16)), z1);
      }
      zs[slot][j*2]   = z0 * (1.f/6.f);
      zs[slot][j*2+1] = z1 * (1.f/6.f);
      // same-wave produce/consume of zs[slot]: no block barrier needed
      float acc = 0.f;
      for (int k = 0; k < DD; k += 4){
        float4 wv = *(const float4*)(Wt_dec + ((size_t)(k>>2)*64 + j)*4);
        acc += zs[slot][k]*wv.x + zs[slot][k+1]*wv.y + zs[slot][k+2]*wv.z + zs[slot][k+3]*wv.w;
      }
      y1[(size_t)n*64 + j] = acc;
      s += acc; q += acc*acc;
    }
  }
  __shared__ float red[2][4][64];
  red[0][slot][j] = s; red[1][slot][j] = q;
  __syncthreads();
  if (slot == 0){
    s = red[0][0][j] + red[0][1][j] + red[0][2][j] + red[0][3][j];
    q = red[1][0][j] + red[1][1][j] + red[1][2][j] + red[1][3][j];
    float* st = stats_d + (size_t)(blockIdx.x & 7)*128;
    atomicAdd(&st[j], s);
    atomicAdd(&st[64+j], q);
  }
}

// ---------- decoder stage 2: sum stats copies, bn + relu + dot ----------
__global__ void __launch_bounds__(256) k_dec2(const float* __restrict__ y1,
        const float* __restrict__ gamma, const float* __restrict__ beta,
        const float* __restrict__ W_dec2, const float* __restrict__ stats_d,
        float* __restrict__ out, int N){
  const int j = threadIdx.x & 63;
  const int g = threadIdx.x >> 6;
  const int n = blockIdx.x*4 + g;
  if (n >= N) return;
  float ssum = 0.f, qsum = 0.f;
  #pragma unroll
  for (int c = 0; c < 8; c++){
    ssum += stats_d[c*128 + j];
    qsum += stats_d[c*128 + 64 + j];
  }
  float invN = 1.f / (float)N;
  float mu = ssum * invN;
  float var = qsum * invN - mu*mu;
  float v = (y1[(size_t)n*64 + j] - mu) * rsqrtf(var + 1e-5f) * gamma[j] + beta[j];
  v = fmaxf(v, 0.f) * W_dec2[j];
  for (int off = 32; off > 0; off >>= 1) v += __shfl_down(v, off, 64);
  if (j == 0) out[n] = v;
}

extern "C" void kernel_launch(void* const* d_in, const int* in_sizes, int n_in,
                              void* d_out, int out_size, void* d_ws, size_t ws_size,
                              hipStream_t stream) {
  const int N = in_sizes[0] / 3;
  const int E = in_sizes[1] / 2;
  const int P = (N + 255) / 256;
  const int HIST_B = (E + 255) / 256;
  const int AB = (N*DD + 255) / 256;

  const float* x     = (const float*)d_in[0];
  const int*   ei    = (const int*)d_in[1];
  const int*   src   = ei;
  const int*   dst   = ei + E;
  const float* norm  = (const float*)d_in[2];
  const float* W_enc = (const float*)d_in[3];
  const float* g_e   = (const float*)d_in[4];
  const float* b_e   = (const float*)d_in[5];
  const float* W_ih  = (const float*)d_in[6];
  const float* W_hh  = (const float*)d_in[7];
  const float* b_ih  = (const float*)d_in[8];
  const float* b_hh  = (const float*)d_in[9];
  const float* W_dec = (const float*)d_in[10];
  const float* g_d   = (const float*)d_in[11];
  const float* b_d   = (const float*)d_in[12];
  const float* W_dec2= (const float*)d_in[13];
  float* out = (float*)d_out;

  float* ws = (float*)d_ws;
  const size_t NF = (size_t)N * DD;
  float* scr    = ws;                        // NF fp32: raw h0 (pre) / y1 (decode)
  float* stats  = scr + NF;                  // 256 enc + 1024 dec
  float* Wt_dec = stats + 1280;              // 64*128
  unsigned short* Wih_hi = (unsigned short*)(Wt_dec + 64*128);
  unsigned short* Wih_lo = Wih_hi + 384*128;
  unsigned short* Whh_hi = Wih_lo + 384*128;
  unsigned short* Whh_lo = Whh_hi + 384*128;
  unsigned short* ph_hiA = Whh_lo + 384*128; // NF ushorts each
  unsigned short* ph_hiB = ph_hiA + NF;
  unsigned short* hbn_bf = ph_hiB + NF;      // NF ushorts (post-BN h, decoder term)
  unsigned short* aggs   = hbn_bf + NF;      // 4 * NF ushorts (layers 0..3)
  int*   counts  = (int*)(aggs + 4*NF);      // N
  int*   offsets = counts + N;               // N+1
  int*   cursors = offsets + N + 1;          // N
  int*   partials= cursors + N;              // P
  int2*  csr     = (int2*)(partials + P);    // E int2 (src, norm-bits)
  float* y1 = scr;                           // scr dead after k_pre2 consumed h0

  hipMemsetAsync(stats, 0, 1280*sizeof(float), stream);
  hipMemsetAsync(counts, 0, (size_t)N*sizeof(int), stream);

  k_pre1<<<PREP_B + 256 + HIST_B, 256, 0, stream>>>(
      W_ih, W_hh, W_dec, x, W_enc, dst,
      Wih_hi, Wih_lo, Whh_hi, Whh_lo, Wt_dec, scr, stats, counts, N, E);
  k_scan_part<<<P, 256, 0, stream>>>(counts, partials, N);
  k_scan_mid<<<1, 256, 0, stream>>>(partials, P, offsets, N);
  k_scan_expand<<<P, 256, 0, stream>>>(counts, partials, offsets, cursors, N);
  k_pre2<<<AB + HIST_B, 256, 0, stream>>>(
      scr, g_e, b_e, stats, ph_hiA, hbn_bf,
      src, dst, norm, cursors, csr, N, E, AB);

  unsigned short* phh_c = ph_hiA;
  unsigned short* phh_n = ph_hiB;
  for (int l = 0; l < 4; l++){
    k_layer<<<(N + 31)/32, 256, 0, stream>>>(phh_c, phh_n, aggs + (size_t)l*NF,
                                             offsets, csr,
                                             Wih_hi, Wih_lo, Whh_hi, Whh_lo, b_ih, b_hh, N);
    unsigned short* t = phh_c; phh_c = phh_n; phh_n = t;
  }

  k_dec1<<<1024, 256, 0, stream>>>(hbn_bf, aggs, NF, phh_c, offsets, csr,
                                   Wt_dec, y1, stats + 256, N);
  k_dec2<<<(N + 3)/4, 256, 0, stream>>>(y1, g_d, b_d, W_dec2, stats + 256, out, N);
}

// Round 12
// 567.329 us; speedup vs baseline: 1.3409x; 1.0681x over previous
//
#include <hip/hip_runtime.h>
#include <hip/hip_bf16.h>

#define DD 128

typedef short bf16x8 __attribute__((ext_vector_type(8)));
typedef unsigned short u16x8 __attribute__((ext_vector_type(8)));
typedef float f32x4 __attribute__((ext_vector_type(4)));

__device__ __forceinline__ float sigmoidf_(float v){ return 1.f/(1.f+__expf(-v)); }
__device__ __forceinline__ float tanhf_(float v){
  float e2 = __expf(2.f*v);
  return 1.f - 2.f/(e2 + 1.f);
}
__device__ __forceinline__ float b2f(unsigned short u){
  unsigned int x = ((unsigned int)u) << 16;
  union { unsigned int i; float f; } c; c.i = x; return c.f;
}
__device__ __forceinline__ void bsplit(float v, unsigned short& hi, unsigned short& lo){
  __hip_bfloat16 h = __float2bfloat16(v);
  float hf = __bfloat162float(h);
  __hip_bfloat16 l = __float2bfloat16(v - hf);
  hi = *(unsigned short*)&h;
  lo = *(unsigned short*)&l;
}
__device__ __forceinline__ unsigned short f2b(float v){
  __hip_bfloat16 h = __float2bfloat16(v);
  return *(unsigned short*)&h;
}

// ---------- fused pre-pass 1: weight prep  ∪  encoder matvec+stats  ∪  dst histogram ----------
#define PREP_B 416   // (2*384*128 + 64*128)/256
__global__ void __launch_bounds__(256) k_pre1(
        const float* __restrict__ W_ih, const float* __restrict__ W_hh,
        const float* __restrict__ W_dec, const float* __restrict__ x,
        const float* __restrict__ W_enc, const int* __restrict__ dst,
        unsigned short* __restrict__ Wih_hi, unsigned short* __restrict__ Wih_lo,
        unsigned short* __restrict__ Whh_hi, unsigned short* __restrict__ Whh_lo,
        float* __restrict__ Wt_dec, float* __restrict__ h0, float* __restrict__ stats,
        int* __restrict__ counts, int N, int E){
  const int tid = threadIdx.x;
  const int gb = blockIdx.x;
  const int TOT = 384*128;
  if (gb < PREP_B){
    int idx = gb*256 + tid;
    if (idx < 2*TOT){
      const float* W = (idx < TOT) ? W_ih : W_hh;
      unsigned short* Dh = (idx < TOT) ? Wih_hi : Whh_hi;
      unsigned short* Dl = (idx < TOT) ? Wih_lo : Whh_lo;
      int fi = (idx < TOT) ? idx : idx - TOT;
      int t = fi & 7;
      int l = (fi >> 3) & 63;
      int ks = (fi >> 9) & 3;
      int nt = fi >> 11;
      int fg = nt / 3, gate = nt % 3;
      int j = gate*128 + fg*16 + (l & 15);
      int k = ks*32 + ((l >> 4) & 3)*8 + t;
      unsigned short hi, lo;
      bsplit(W[j*128 + k], hi, lo);
      Dh[fi] = hi; Dl[fi] = lo;
    } else if (idx < 2*TOT + 64*128){
      int t2 = idx - 2*TOT;
      int j = t2 / 128, k = t2 % 128;
      int o = ((k>>2)*64 + j)*4 + (k&3);
      Wt_dec[o] = W_dec[t2];
    }
  } else if (gb < PREP_B + 256){
    const int b = gb - PREP_B;
    const int f = tid & 127;
    const int sub = tid >> 7;
    const float w0 = W_enc[f*3], w1 = W_enc[f*3+1], w2 = W_enc[f*3+2];
    const int chunk = (N + 255) / 256;
    const int n0 = b * chunk;
    const int n1 = (n0 + chunk < N) ? (n0 + chunk) : N;
    float s = 0.f, q = 0.f;
    for (int n = n0 + sub; n < n1; n += 2){
      float x0 = x[n*3], x1 = x[n*3+1], x2 = x[n*3+2];
      float h = x0*w0 + x1*w1 + x2*w2;
      h0[(size_t)n*DD + f] = h;
      s += h; q += h*h;
    }
    atomicAdd(&stats[f], s);
    atomicAdd(&stats[DD+f], q);
  } else {
    int e = (gb - PREP_B - 256)*256 + tid;
    if (e < E) atomicAdd(&counts[dst[e]], 1);
  }
}

// ---------- scan chain ----------
__global__ void __launch_bounds__(256) k_scan_part(const int* __restrict__ counts,
                                                   int* __restrict__ partials, int N){
  int i = blockIdx.x*256 + threadIdx.x;
  int v = (i < N) ? counts[i] : 0;
  #pragma unroll
  for (int off = 32; off > 0; off >>= 1) v += __shfl_down(v, off, 64);
  __shared__ int red[4];
  if ((threadIdx.x & 63) == 0) red[threadIdx.x >> 6] = v;
  __syncthreads();
  if (threadIdx.x == 0) partials[blockIdx.x] = red[0]+red[1]+red[2]+red[3];
}

__global__ void __launch_bounds__(256) k_scan_mid(int* __restrict__ partials, int P,
                                                  int* __restrict__ offsets, int N){
  __shared__ int lds[4];
  __shared__ int carry_s;
  const int lane = threadIdx.x & 63, wid = threadIdx.x >> 6;
  if (threadIdx.x == 0) carry_s = 0;
  __syncthreads();
  for (int base = 0; base < P; base += 256){
    int i = base + threadIdx.x;
    int v = (i < P) ? partials[i] : 0;
    int orig = v;
    #pragma unroll
    for (int off = 1; off < 64; off <<= 1){
      int u = __shfl_up(v, off, 64);
      if (lane >= off) v += u;
    }
    if (lane == 63) lds[wid] = v;
    __syncthreads();
    if (threadIdx.x == 0){
      int s = carry_s;
      for (int k = 0; k < 4; k++){ int t = lds[k]; lds[k] = s; s += t; }
      carry_s = s;
    }
    __syncthreads();
    int excl = v - orig + lds[wid];
    if (i < P) partials[i] = excl;
    __syncthreads();
  }
  if (threadIdx.x == 0) offsets[N] = carry_s;
}

__global__ void __launch_bounds__(256) k_scan_expand(const int* __restrict__ counts,
        const int* __restrict__ partials, int* __restrict__ offsets,
        int* __restrict__ cursors, int N){
  int i = blockIdx.x*256 + threadIdx.x;
  int v = (i < N) ? counts[i] : 0;
  int orig = v;
  const int lane = threadIdx.x & 63, wid = threadIdx.x >> 6;
  #pragma unroll
  for (int off = 1; off < 64; off <<= 1){
    int u = __shfl_up(v, off, 64);
    if (lane >= off) v += u;
  }
  __shared__ int lds[4];
  if (lane == 63) lds[wid] = v;
  __syncthreads();
  int wbase = 0;
  for (int k = 0; k < wid; k++) wbase += lds[k];
  int excl = partials[blockIdx.x] + wbase + v - orig;
  if (i < N){ offsets[i] = excl; cursors[i] = excl; }
}

// ---------- fused pre-pass 2: BN+ReLU apply  ∪  CSR fill ----------
__global__ void __launch_bounds__(256) k_pre2(
        const float* __restrict__ h0, const float* __restrict__ gamma,
        const float* __restrict__ beta, const float* __restrict__ stats,
        unsigned short* __restrict__ ph_hi, unsigned short* __restrict__ hbn_bf,
        const int* __restrict__ src, const int* __restrict__ dst,
        const float* __restrict__ norm, int* __restrict__ cursors,
        int2* __restrict__ csr, int N, int E, int AB){
  const int tid = threadIdx.x;
  if ((int)blockIdx.x < AB){
    int idx = blockIdx.x*256 + tid;
    if (idx >= N*DD) return;
    int f = idx & (DD-1);
    float invN = 1.f / (float)N;
    float mu = stats[f] * invN;
    float var = stats[DD+f] * invN - mu*mu;
    float v = (h0[idx] - mu) * rsqrtf(var + 1e-5f) * gamma[f] + beta[f];
    v = fmaxf(v, 0.f);
    unsigned short hi = f2b(v);
    ph_hi[idx] = hi;
    hbn_bf[idx] = hi;
  } else {
    int e = ((int)blockIdx.x - AB)*256 + tid;
    if (e >= E) return;
    int p = atomicAdd(&cursors[dst[e]], 1);
    union { float f; int i; } c; c.f = norm[e];
    csr[p] = make_int2(src[e], c.i);
  }
}

// ---------- fused layer (0..3): bf16 gather -> LDS -> MFMA -> gates ----------
__global__ void __launch_bounds__(256, 4) k_layer(
        const unsigned short* __restrict__ phc_hi,
        unsigned short* __restrict__ phn_hi,
        unsigned short* __restrict__ agg_out,
        const int* __restrict__ offsets, const int2* __restrict__ csr,
        const unsigned short* __restrict__ Wih_hi, const unsigned short* __restrict__ Wih_lo,
        const unsigned short* __restrict__ Whh_hi, const unsigned short* __restrict__ Whh_lo,
        const float* __restrict__ b_ih, const float* __restrict__ b_hh, int N){
  __shared__ unsigned short s_ah[32*DD];
  __shared__ unsigned short s_al[32*DD];
  const int tid = threadIdx.x;
  const int n0 = blockIdx.x * 32;

  // ---- phase 1: gather (bf16 rows) ----
  {
    const int slot = tid >> 4;   // node slot 0..15
    const int q    = tid & 15;   // feature octet
    #pragma unroll
    for (int pass = 0; pass < 2; pass++){
      const int m = slot + pass*16;
      const int n = n0 + m;
      float acc[8];
      #pragma unroll
      for (int t = 0; t < 8; t++) acc[t] = 0.f;
      if (n < N){
        const int s0 = offsets[n], s1 = offsets[n+1];
        int i = s0;
        for (; i + 8 <= s1; i += 8){
          int2 ed[8]; bf16x8 R[8];
          #pragma unroll
          for (int u = 0; u < 8; u++) ed[u] = csr[i+u];
          #pragma unroll
          for (int u = 0; u < 8; u++) R[u] = *(const bf16x8*)(phc_hi + (size_t)ed[u].x*DD + q*8);
          #pragma unroll
          for (int u = 0; u < 8; u++){
            union { int i; float f; } c; c.i = ed[u].y;
            #pragma unroll
            for (int t = 0; t < 8; t++)
              acc[t] = fmaf(c.f, b2f((unsigned short)R[u][t]), acc[t]);
          }
        }
        if (i + 4 <= s1){
          int2 ed[4]; bf16x8 R[4];
          #pragma unroll
          for (int u = 0; u < 4; u++) ed[u] = csr[i+u];
          #pragma unroll
          for (int u = 0; u < 4; u++) R[u] = *(const bf16x8*)(phc_hi + (size_t)ed[u].x*DD + q*8);
          #pragma unroll
          for (int u = 0; u < 4; u++){
            union { int i; float f; } c; c.i = ed[u].y;
            #pragma unroll
            for (int t = 0; t < 8; t++)
              acc[t] = fmaf(c.f, b2f((unsigned short)R[u][t]), acc[t]);
          }
          i += 4;
        }
        for (; i < s1; i++){
          int2 ed = csr[i];
          union { int i; float f; } c; c.i = ed.y;
          bf16x8 R = *(const bf16x8*)(phc_hi + (size_t)ed.x*DD + q*8);
          #pragma unroll
          for (int t = 0; t < 8; t++)
            acc[t] = fmaf(c.f, b2f((unsigned short)R[t]), acc[t]);
        }
      }
      u16x8 vhi, vlo;
      #pragma unroll
      for (int t = 0; t < 8; t++){
        unsigned short hi, lo; bsplit(acc[t], hi, lo);
        vhi[t] = hi; vlo[t] = lo;
      }
      if (n < N)
        *(u16x8*)(agg_out + (size_t)n*DD + q*8) = vhi;   // write-only, for decoder
      const int cc = q ^ (m & 7);
      const int off = m*DD + cc*8;
      *(u16x8*)(s_ah + off) = vhi;
      *(u16x8*)(s_al + off) = vlo;
    }
  }
  __syncthreads();   // the only barrier: LDS A-frags ready

  // ---- phase 2+3 per feature group ----
  const int w = tid >> 6, l = tid & 63, ar = l & 15, aq = l >> 4;
  int r0 = n0 + ar;      if (r0 >= N) r0 = N-1;
  int r1 = n0 + 16 + ar; if (r1 >= N) r1 = N-1;
  const size_t p0 = (size_t)r0*DD + aq*8;
  const size_t p1 = (size_t)r1*DD + aq*8;
  const int sw = ar & 7;

  for (int g = 0; g < 2; g++){
    const int fg = w*2 + g;
    f32x4 acc_i[2][3], acc_h[2][3];
    #pragma unroll
    for (int ta = 0; ta < 2; ta++)
      #pragma unroll
      for (int t = 0; t < 3; t++){
        acc_i[ta][t] = (f32x4){0.f,0.f,0.f,0.f};
        acc_h[ta][t] = (f32x4){0.f,0.f,0.f,0.f};
      }

    #pragma unroll
    for (int ks = 0; ks < 4; ks++){
      const int c = (ks*4 + aq) ^ sw;
      bf16x8 ih0 = *(const bf16x8*)(s_ah + ar*DD       + c*8);
      bf16x8 ih1 = *(const bf16x8*)(s_ah + (16+ar)*DD  + c*8);
      bf16x8 il0 = *(const bf16x8*)(s_al + ar*DD       + c*8);
      bf16x8 il1 = *(const bf16x8*)(s_al + (16+ar)*DD  + c*8);
      bf16x8 hh0 = *(const bf16x8*)(phc_hi + p0 + ks*32);
      bf16x8 hh1 = *(const bf16x8*)(phc_hi + p1 + ks*32);
      #pragma unroll
      for (int t = 0; t < 3; t++){
        size_t bo = ((size_t)((fg*3 + t)*4 + ks)*64 + l)*8;
        bf16x8 bih = *(const bf16x8*)(Wih_hi + bo);
        bf16x8 bil = *(const bf16x8*)(Wih_lo + bo);
        bf16x8 bhh = *(const bf16x8*)(Whh_hi + bo);
        bf16x8 bhl = *(const bf16x8*)(Whh_lo + bo);
        acc_i[0][t] = __builtin_amdgcn_mfma_f32_16x16x32_bf16(ih0, bih, acc_i[0][t], 0, 0, 0);
        acc_i[0][t] = __builtin_amdgcn_mfma_f32_16x16x32_bf16(ih0, bil, acc_i[0][t], 0, 0, 0);
        acc_i[0][t] = __builtin_amdgcn_mfma_f32_16x16x32_bf16(il0, bih, acc_i[0][t], 0, 0, 0);
        acc_i[1][t] = __builtin_amdgcn_mfma_f32_16x16x32_bf16(ih1, bih, acc_i[1][t], 0, 0, 0);
        acc_i[1][t] = __builtin_amdgcn_mfma_f32_16x16x32_bf16(ih1, bil, acc_i[1][t], 0, 0, 0);
        acc_i[1][t] = __builtin_amdgcn_mfma_f32_16x16x32_bf16(il1, bih, acc_i[1][t], 0, 0, 0);
        acc_h[0][t] = __builtin_amdgcn_mfma_f32_16x16x32_bf16(hh0, bhh, acc_h[0][t], 0, 0, 0);
        acc_h[0][t] = __builtin_amdgcn_mfma_f32_16x16x32_bf16(hh0, bhl, acc_h[0][t], 0, 0, 0);
        acc_h[1][t] = __builtin_amdgcn_mfma_f32_16x16x32_bf16(hh1, bhh, acc_h[1][t], 0, 0, 0);
        acc_h[1][t] = __builtin_amdgcn_mfma_f32_16x16x32_bf16(hh1, bhl, acc_h[1][t], 0, 0, 0);
      }
    }

    const int f = fg*16 + ar;
    const float bir = b_ih[f], biz = b_ih[128+f], bin_ = b_ih[256+f];
    const float bhr = b_hh[f], bhz = b_hh[128+f], bhn = b_hh[256+f];
    #pragma unroll
    for (int ta = 0; ta < 2; ta++){
      #pragma unroll
      for (int r = 0; r < 4; r++){
        int n = n0 + ta*16 + aq*4 + r;
        if (n < N){
          float sir = acc_i[ta][0][r] + bir, shr = acc_h[ta][0][r] + bhr;
          float siz = acc_i[ta][1][r] + biz, shz = acc_h[ta][1][r] + bhz;
          float sin_ = acc_i[ta][2][r] + bin_, shn = acc_h[ta][2][r] + bhn;
          float rr = sigmoidf_(sir + shr);
          float zz = sigmoidf_(siz + shz);
          float nn = tanhf_(sin_ + rr*shn);
          size_t o = (size_t)n*DD + f;
          float hp = b2f(phc_hi[o]);
          float h = (1.f - zz)*nn + zz*hp;
          phn_hi[o] = f2b(h);
        }
      }
    }
  }
}

// ---------- decoder stage 1 (fused layer-5 gather, k_layer-shaped): ----------
// Phase A: 16-lane x 16B gather per node (32 nodes/block) + hbn + 4 aggs -> z in LDS.
// Phase B: 4 waves x 8 nodes matvec (zs broadcast reads), stats block-reduce.
__global__ void __launch_bounds__(256) k_dec1(const unsigned short* __restrict__ hbn,
        const unsigned short* __restrict__ aggs, size_t NF,
        const unsigned short* __restrict__ ph5,
        const int* __restrict__ offsets, const int2* __restrict__ csr,
        const float* __restrict__ Wt_dec, float* __restrict__ y1,
        float* __restrict__ stats_d, int N){
  __shared__ float zs[32][DD];
  const int tid = threadIdx.x;
  const int n0 = blockIdx.x * 32;

  // ---- phase A: gather + layer-sum ----
  {
    const int slot = tid >> 4;   // node slot 0..15
    const int q    = tid & 15;   // feature octet
    #pragma unroll
    for (int pass = 0; pass < 2; pass++){
      const int m = slot + pass*16;
      const int n = n0 + m;
      float acc[8];
      #pragma unroll
      for (int t = 0; t < 8; t++) acc[t] = 0.f;
      if (n < N){
        size_t o = (size_t)n*DD + q*8;
        u16x8 hb = *(const u16x8*)(hbn + o);
        #pragma unroll
        for (int t = 0; t < 8; t++) acc[t] = b2f(hb[t]);
        #pragma unroll
        for (int l = 0; l < 4; l++){
          u16x8 ag = *(const u16x8*)(aggs + l*NF + o);
          #pragma unroll
          for (int t = 0; t < 8; t++) acc[t] += b2f(ag[t]);
        }
        const int s0 = offsets[n], s1 = offsets[n+1];
        int i = s0;
        for (; i + 8 <= s1; i += 8){
          int2 ed[8]; bf16x8 R[8];
          #pragma unroll
          for (int u = 0; u < 8; u++) ed[u] = csr[i+u];
          #pragma unroll
          for (int u = 0; u < 8; u++) R[u] = *(const bf16x8*)(ph5 + (size_t)ed[u].x*DD + q*8);
          #pragma unroll
          for (int u = 0; u < 8; u++){
            union { int i; float f; } c; c.i = ed[u].y;
            #pragma unroll
            for (int t = 0; t < 8; t++)
              acc[t] = fmaf(c.f, b2f((unsigned short)R[u][t]), acc[t]);
          }
        }
        if (i + 4 <= s1){
          int2 ed[4]; bf16x8 R[4];
          #pragma unroll
          for (int u = 0; u < 4; u++) ed[u] = csr[i+u];
          #pragma unroll
          for (int u = 0; u < 4; u++) R[u] = *(const bf16x8*)(ph5 + (size_t)ed[u].x*DD + q*8);
          #pragma unroll
          for (int u = 0; u < 4; u++){
            union { int i; float f; } c; c.i = ed[u].y;
            #pragma unroll
            for (int t = 0; t < 8; t++)
              acc[t] = fmaf(c.f, b2f((unsigned short)R[u][t]), acc[t]);
          }
          i += 4;
        }
        for (; i < s1; i++){
          int2 ed = csr[i];
          union { int i; float f; } c; c.i = ed.y;
          bf16x8 R = *(const bf16x8*)(ph5 + (size_t)ed.x*DD + q*8);
          #pragma unroll
          for (int t = 0; t < 8; t++)
            acc[t] = fmaf(c.f, b2f((unsigned short)R[t]), acc[t]);
        }
      }
      #pragma unroll
      for (int t = 0; t < 8; t++) zs[m][q*8 + t] = acc[t] * (1.f/6.f);
    }
  }
  __syncthreads();

  // ---- phase B: matvec (wave w -> nodes w*8..w*8+7), stats ----
  const int w = tid >> 6, j = tid & 63;
  float s = 0.f, q = 0.f;
  #pragma unroll
  for (int it = 0; it < 8; it++){
    const int m = w*8 + it;
    const int n = n0 + m;
    if (n < N){
      float acc = 0.f;
      for (int k = 0; k < DD; k += 4){
        float4 wv = *(const float4*)(Wt_dec + ((size_t)(k>>2)*64 + j)*4);
        acc += zs[m][k]*wv.x + zs[m][k+1]*wv.y + zs[m][k+2]*wv.z + zs[m][k+3]*wv.w;
      }
      y1[(size_t)n*64 + j] = acc;
      s += acc; q += acc*acc;
    }
  }
  __shared__ float red[2][4][64];
  red[0][w][j] = s; red[1][w][j] = q;
  __syncthreads();
  if (w == 0){
    s = red[0][0][j] + red[0][1][j] + red[0][2][j] + red[0][3][j];
    q = red[1][0][j] + red[1][1][j] + red[1][2][j] + red[1][3][j];
    float* st = stats_d + (size_t)(blockIdx.x & 7)*128;
    atomicAdd(&st[j], s);
    atomicAdd(&st[64+j], q);
  }
}

// ---------- decoder stage 2: sum stats copies, bn + relu + dot ----------
__global__ void __launch_bounds__(256) k_dec2(const float* __restrict__ y1,
        const float* __restrict__ gamma, const float* __restrict__ beta,
        const float* __restrict__ W_dec2, const float* __restrict__ stats_d,
        float* __restrict__ out, int N){
  const int j = threadIdx.x & 63;
  const int g = threadIdx.x >> 6;
  const int n = blockIdx.x*4 + g;
  if (n >= N) return;
  float ssum = 0.f, qsum = 0.f;
  #pragma unroll
  for (int c = 0; c < 8; c++){
    ssum += stats_d[c*128 + j];
    qsum += stats_d[c*128 + 64 + j];
  }
  float invN = 1.f / (float)N;
  float mu = ssum * invN;
  float var = qsum * invN - mu*mu;
  float v = (y1[(size_t)n*64 + j] - mu) * rsqrtf(var + 1e-5f) * gamma[j] + beta[j];
  v = fmaxf(v, 0.f) * W_dec2[j];
  for (int off = 32; off > 0; off >>= 1) v += __shfl_down(v, off, 64);
  if (j == 0) out[n] = v;
}

extern "C" void kernel_launch(void* const* d_in, const int* in_sizes, int n_in,
                              void* d_out, int out_size, void* d_ws, size_t ws_size,
                              hipStream_t stream) {
  const int N = in_sizes[0] / 3;
  const int E = in_sizes[1] / 2;
  const int P = (N + 255) / 256;
  const int HIST_B = (E + 255) / 256;
  const int AB = (N*DD + 255) / 256;

  const float* x     = (const float*)d_in[0];
  const int*   ei    = (const int*)d_in[1];
  const int*   src   = ei;
  const int*   dst   = ei + E;
  const float* norm  = (const float*)d_in[2];
  const float* W_enc = (const float*)d_in[3];
  const float* g_e   = (const float*)d_in[4];
  const float* b_e   = (const float*)d_in[5];
  const float* W_ih  = (const float*)d_in[6];
  const float* W_hh  = (const float*)d_in[7];
  const float* b_ih  = (const float*)d_in[8];
  const float* b_hh  = (const float*)d_in[9];
  const float* W_dec = (const float*)d_in[10];
  const float* g_d   = (const float*)d_in[11];
  const float* b_d   = (const float*)d_in[12];
  const float* W_dec2= (const float*)d_in[13];
  float* out = (float*)d_out;

  float* ws = (float*)d_ws;
  const size_t NF = (size_t)N * DD;
  float* scr    = ws;                        // NF fp32: raw h0 (pre) / y1 (decode)
  float* stats  = scr + NF;                  // 256 enc + 1024 dec
  float* Wt_dec = stats + 1280;              // 64*128
  unsigned short* Wih_hi = (unsigned short*)(Wt_dec + 64*128);
  unsigned short* Wih_lo = Wih_hi + 384*128;
  unsigned short* Whh_hi = Wih_lo + 384*128;
  unsigned short* Whh_lo = Whh_hi + 384*128;
  unsigned short* ph_hiA = Whh_lo + 384*128; // NF ushorts each
  unsigned short* ph_hiB = ph_hiA + NF;
  unsigned short* hbn_bf = ph_hiB + NF;      // NF ushorts (post-BN h, decoder term)
  unsigned short* aggs   = hbn_bf + NF;      // 4 * NF ushorts (layers 0..3)
  int*   counts  = (int*)(aggs + 4*NF);      // N
  int*   offsets = counts + N;               // N+1
  int*   cursors = offsets + N + 1;          // N
  int*   partials= cursors + N;              // P
  int2*  csr     = (int2*)(partials + P);    // E int2 (src, norm-bits)
  float* y1 = scr;                           // scr dead after k_pre2 consumed h0

  hipMemsetAsync(stats, 0, 1280*sizeof(float), stream);
  hipMemsetAsync(counts, 0, (size_t)N*sizeof(int), stream);

  k_pre1<<<PREP_B + 256 + HIST_B, 256, 0, stream>>>(
      W_ih, W_hh, W_dec, x, W_enc, dst,
      Wih_hi, Wih_lo, Whh_hi, Whh_lo, Wt_dec, scr, stats, counts, N, E);
  k_scan_part<<<P, 256, 0, stream>>>(counts, partials, N);
  k_scan_mid<<<1, 256, 0, stream>>>(partials, P, offsets, N);
  k_scan_expand<<<P, 256, 0, stream>>>(counts, partials, offsets, cursors, N);
  k_pre2<<<AB + HIST_B, 256, 0, stream>>>(
      scr, g_e, b_e, stats, ph_hiA, hbn_bf,
      src, dst, norm, cursors, csr, N, E, AB);

  unsigned short* phh_c = ph_hiA;
  unsigned short* phh_n = ph_hiB;
  for (int l = 0; l < 4; l++){
    k_layer<<<(N + 31)/32, 256, 0, stream>>>(phh_c, phh_n, aggs + (size_t)l*NF,
                                             offsets, csr,
                                             Wih_hi, Wih_lo, Whh_hi, Whh_lo, b_ih, b_hh, N);
    unsigned short* t = phh_c; phh_c = phh_n; phh_n = t;
  }

  k_dec1<<<(N + 31)/32, 256, 0, stream>>>(hbn_bf, aggs, NF, phh_c, offsets, csr,
                                          Wt_dec, y1, stats + 256, N);
  k_dec2<<<(N + 3)/4, 256, 0, stream>>>(y1, g_d, b_d, W_dec2, stats + 256, out, N);
}